// Round 24
// baseline (421.338 us; speedup 1.0000x reference)
//
#include <hip/hip_runtime.h>
#include <hip/hip_bf16.h>

typedef __hip_bfloat16 bf16;
typedef unsigned short ushort;
typedef __attribute__((ext_vector_type(8))) short short8v;   // 8 bf16 = 4 VGPR
typedef __attribute__((ext_vector_type(4))) float float4v;

__device__ __forceinline__ float b2f(bf16 v){ return __bfloat162float(v); }
__device__ __forceinline__ float sigm(float x){ return 1.0f/(1.0f+__expf(-x)); }
__device__ __forceinline__ float tanhc(float x){
  x = fminf(15.0f, fmaxf(-15.0f, x));
  float e = __expf(2.0f*x);
  return (e-1.0f)/(e+1.0f);
}
__device__ __forceinline__ ushort f2bu(float f){
  bf16 h = __float2bfloat16(f); return *reinterpret_cast<ushort*>(&h);
}
__device__ __forceinline__ float bu2f(ushort u){
  return __uint_as_float(((unsigned)u)<<16);
}
__device__ __forceinline__ short8v ldfrag(const ushort* p){
  return *reinterpret_cast<const short8v*>(p);
}
// direct global->LDS DMA, 16B per lane; lds dst = uniform base + lane*16
__device__ __forceinline__ void glds16(const ushort* g, ushort* l){
  __builtin_amdgcn_global_load_lds(
    (const __attribute__((address_space(1))) unsigned int*)g,
    (__attribute__((address_space(3))) unsigned int*)l, 16, 0, 0);
}

// ---------------------------------------------------------------------------
// ws layout (float offsets)
// ---------------------------------------------------------------------------
#define WS_SMALL   0
#define WS_FLAG    262144
#define WS_ZROW    262160
#define WS_H       262208
#define WS_C       524352
#define WS_M       786496
#define WS_QB16    1310784
#define WS_KHB16   1376320
#define WS_KMB16   1441856
#define WS_VTH16   1507392
#define WS_VTM16   1638464
#define WS_MTH     1769536
#define WS_MTL     1900608
#define WS_HNTH    2031680
#define WS_HNTL    2162752
#define WS_ZW16H   2293824
#define WS_ZW16L   2302016
#define WS_MW16H   2310208
#define WS_MW16L   2328640
#define WS_WXAH    2347072     // 73728 f (147456 ushort) X weights hi
#define WS_WHAH    2420800     // 73728 f h weights hi
#define WS_WXAL    2494528     // 73728 f X weights lo
#define WS_WHAL    2568256     // 73728 f h weights lo
#define WS_XTHI    2641984
#define WS_XTLO    3690560
#define WS_HTHI    4739136
#define WS_HTLO    4870208
#define WS_PWH     5001280
#define WS_PWL     5006912
#define WS_GXG     5012544     // 2097152 f32: g-gate X-partial [bt][64cc][1024]
#define WS_GXO     7109696     // 6291456 ushort: i/f/o X-partials [bt][192][1024]
// total 10255424 f = 41.0 MB (ws known >= 45.2 MB from R2)
// small-weight offsets inside WS_SMALL
#define O_CB    0
#define O_WCI   256
#define O_WCF   65792
#define O_WCO   131328
#define O_QW    196864
#define O_QB    197888
#define O_KW    197904
#define O_KB    198928
#define O_K2W   198944
#define O_K2B   199968
#define O_VW    199984
#define O_VB    204080
#define O_V2W   204144
#define O_V2B   208240
#define O_ZW    208304
#define O_ZB    224688
#define O_MW    224816
#define O_MB    261680

// ---------------------------------------------------------------------------
// dtype probe (f32 vs bf16 input data)
// ---------------------------------------------------------------------------
__global__ void k_probe(const unsigned int* __restrict__ Xu, int* __restrict__ flag){
  __shared__ int cnt;
  if (threadIdx.x == 0) cnt = 0;
  __syncthreads();
  unsigned int u = Xu[threadIdx.x];
  float f = __uint_as_float((u & 0xffffu) << 16);
  int bad = (fabsf(f) <= 1e4f) ? 0 : 1;
  atomicAdd(&cnt, bad);
  __syncthreads();
  if (threadIdx.x == 0) *flag = (cnt > 16) ? 1 : 0;
}

// ---------------------------------------------------------------------------
// convert the 18 small inputs into f32 copies in ws
// ---------------------------------------------------------------------------
struct P18 { const void* p[18]; };

__global__ __launch_bounds__(256) void k_wconv(P18 pk, const int* __restrict__ flagp,
                                               float* __restrict__ dst){
  const int ns[18]   = {256,65536,65536,65536,1024,16,1024,16,1024,16,
                        4096,64,4096,64,16384,128,36864,192};
  const int offs[18] = {O_CB,O_WCI,O_WCF,O_WCO,O_QW,O_QB,O_KW,O_KB,O_K2W,O_K2B,
                        O_VW,O_VB,O_V2W,O_V2B,O_ZW,O_ZB,O_MW,O_MB};
  int y = blockIdx.y;
  int n = ns[y];
  int flag = *flagp;
  const void* src = pk.p[y];
  for (int i = blockIdx.x*256 + threadIdx.x; i < n; i += gridDim.x*256){
    float v = flag ? ((const float*)src)[i] : b2f(((const bf16*)src)[i]);
    dst[offs[y] + i] = v;
  }
}

// bf16 hi/lo copies: z_w (128x128), m_w (192x192), proj weights [176][64]
__global__ __launch_bounds__(256) void k_wtrans(float* __restrict__ ws){
  int i = blockIdx.x*256 + threadIdx.x;
  if (i < 16384){
    float f = ws[O_ZW + i];
    ushort h = f2bu(f);
    ((ushort*)(ws + WS_ZW16H))[i] = h;
    ((ushort*)(ws + WS_ZW16L))[i] = f2bu(f - bu2f(h));
  }
  if (i < 36864){
    float f = ws[O_MW + i];
    ushort h = f2bu(f);
    ((ushort*)(ws + WS_MW16H))[i] = h;
    ((ushort*)(ws + WS_MW16L))[i] = f2bu(f - bu2f(h));
  }
  if (i < 11264){
    int r = i >> 6, k = i & 63;
    float f;
    if (r < 16)       f = ws[O_QW  + r*64 + k];
    else if (r < 32)  f = ws[O_KW  + (r-16)*64 + k];
    else if (r < 48)  f = ws[O_K2W + (r-32)*64 + k];
    else if (r < 112) f = ws[O_VW  + (r-48)*64 + k];
    else              f = ws[O_V2W + (r-112)*64 + k];
    ushort h = f2bu(f);
    ((ushort*)(ws + WS_PWH))[i] = h;
    ((ushort*)(ws + WS_PWL))[i] = f2bu(f - bu2f(h));
  }
}

// ---------------------------------------------------------------------------
// init: zero states + hT + mT + q/k pad; split conv weights into X-only
// (wxa) and h-only (wha) layouts, both chunk-swizzled c ^= (mm&7) over
// 8 chunks of 8 ushort per 64-ci row.
// ---------------------------------------------------------------------------
__global__ __launch_bounds__(256) void k_init(const void* __restrict__ conv_w,
                                              const int* __restrict__ flagp,
                                              float* __restrict__ ws){
  int i = blockIdx.x*256 + threadIdx.x;
  int flag = *flagp;
  if (i < 786432) ws[WS_H + i] = 0.0f;
  if (i < 32) ws[WS_ZROW + i] = 0.0f;
  if (i < 196608) ((unsigned*)(ws + WS_QB16))[i] = 0u;   // qb/kh/km incl. pad
  if (i < 294912){
    int ci = i & 127;
    int j = i >> 7;           // j = p*256 + mm
    int mm = j & 255, p = j >> 8;
    int cc = mm >> 2, g = mm & 3;
    int si = ((g*64 + cc)*128 + ci)*9 + p;
    float f;
    ushort hi, lo = 0;
    if (flag){
      f = ((const float*)conv_w)[si];
      hi = f2bu(f);
      lo = f2bu(f - bu2f(hi));
    } else {
      hi = ((const ushort*)conv_w)[si];
    }
    if (ci < 64){
      int di = (j << 6) + ((((ci >> 3) ^ (mm & 7)) << 3) | (ci & 7));
      ((ushort*)(ws + WS_WXAH))[di] = hi;
      ((ushort*)(ws + WS_WXAL))[di] = lo;
    } else {
      int c2 = ci - 64;
      int di = (j << 6) + ((((c2 >> 3) ^ (mm & 7)) << 3) | (c2 & 7));
      ((ushort*)(ws + WS_WHAH))[di] = hi;
      ((ushort*)(ws + WS_WHAL))[di] = lo;
    }
  }
  if (i < 131072){
    ((unsigned*)(ws + WS_HTHI))[i] = 0u;
    ((unsigned*)(ws + WS_HTLO))[i] = 0u;
    ((unsigned*)(ws + WS_MTH))[i] = 0u;
    ((unsigned*)(ws + WS_MTL))[i] = 0u;
  }
}

// ---------------------------------------------------------------------------
// X transpose: XT[b][t][px][ci]
// ---------------------------------------------------------------------------
__global__ __launch_bounds__(256) void k_xt(const void* __restrict__ Xraw,
                                            const int* __restrict__ flagp,
                                            float* __restrict__ ws){
  __shared__ ushort hi_s[64][66];
  __shared__ ushort lo_s[64][66];
  int pt = blockIdx.x, s = blockIdx.y;
  int b = s >> 3, t = s & 7;
  int flag = *flagp;
  int tid = threadIdx.x;
  for (int k = 0; k < 16; ++k){
    int idx = tid + k*256;
    int ci = idx >> 6, pxl = idx & 63;
    size_t si = ((size_t)(b*64 + ci)*8 + t)*1024 + pt*64 + pxl;
    if (flag){
      float f = ((const float*)Xraw)[si];
      ushort h = f2bu(f);
      hi_s[pxl][ci] = h;
      lo_s[pxl][ci] = f2bu(f - bu2f(h));
    } else {
      hi_s[pxl][ci] = ((const ushort*)Xraw)[si];
    }
  }
  __syncthreads();
  ushort* xh = (ushort*)(ws + WS_XTHI) + ((size_t)s*1024 + pt*64)*64;
  ushort* xl = (ushort*)(ws + WS_XTLO) + ((size_t)s*1024 + pt*64)*64;
  for (int k = 0; k < 16; ++k){
    int idx = tid + k*256;
    int pxl = idx >> 6, ci = idx & 63;
    xh[pxl*64 + ci] = hi_s[pxl][ci];
    if (flag) xl[pxl*64 + ci] = lo_s[pxl][ci];
  }
}

// ---------------------------------------------------------------------------
// k_convx: time-invariant X-part of the conv gates for ALL (b,t) at once.
// grid (64 nt, 2 mh, 32 bt) = 4096 blocks, block 512 = 8 waves.
// R24: DOUBLE-BUFFERED A + counted vmcnt(2) — occupancy-neutral this time:
// halo is statically hi-only (stride 72, 7.8 KB) since the hot path never
// reads lo; A dbuf 32 KB -> total 39.6 KB -> still 4 blocks/CU (wave cap).
// (R19's regression was the 47.6 KB LDS dropping occupancy to 3 blocks.)
// Cold f32 path: two serial passes (hi-halo: Ahi*Bhi + Alo*Bhi; restage
// lo-halo: Ahi*Blo) — correct, never hot.
// ---------------------------------------------------------------------------
__global__ __launch_bounds__(512, 4) void k_convx(
  const int* __restrict__ flagp,
  const ushort* __restrict__ wxah, const ushort* __restrict__ wxal,
  const ushort* __restrict__ xt_hi, const ushort* __restrict__ xt_lo,
  float* __restrict__ gxg, ushort* __restrict__ gxo)
{
  __shared__ ushort xabuf[16384];    // 2 buffers x 8 waves x 1024 ushort
  __shared__ ushort xsm[54*72];      // halo, ONE precision at a time
  int nt = blockIdx.x, mh = blockIdx.y, tb = blockIdx.z;
  int tid = threadIdx.x;
  int flag = *flagp;
  int ytile = nt >> 1, x0 = (nt & 1) * 16;
  const ushort* xb  = xt_hi + (size_t)tb*65536;
  const ushort* xlb = xt_lo + (size_t)tb*65536;
  int w = tid >> 6, lane = tid & 63, lr = lane & 15, lk = lane >> 4;
  const ushort* aw  = wxah + (size_t)(mh*128 + w*16)*64 + lane*8;  // + p*16384
  const ushort* awl = wxal + (size_t)(mh*128 + w*16)*64 + lane*8;
  ushort* buf0 = xabuf + w*1024;
  ushort* buf1 = xabuf + 8192 + w*1024;

  const uint4 Z16 = make_uint4(0,0,0,0);

  if (!flag){
    // prefetch A(0); drained by the halo barrier
    glds16(aw, buf0);
    glds16(aw + 512, buf0 + 512);
  }

  // stage hi halo: 54 slots x 8 chunks of 16B (pad [64,72) never read)
  for (int idx = tid; idx < 432; idx += 512){
    int slot = idx >> 3, c = idx & 7;
    int rr = slot / 18, xi = slot - rr*18;
    int gy = ytile - 1 + rr, gx2 = x0 - 1 + xi;
    bool valid = (gy >= 0) & (gy < 32) & (gx2 >= 0) & (gx2 < 32);
    int px = gy*32 + gx2;
    uint4 v = valid ? *reinterpret_cast<const uint4*>(xb + (size_t)px*64 + c*8) : Z16;
    *reinterpret_cast<uint4*>(&xsm[slot*72 + c*8]) = v;
  }
  __syncthreads();   // drains vmcnt+lgkmcnt -> A(0) resident, waits exact

  int px = nt*16 + lr;
  int sw = lr & 7;
  const int cx0 = ((lk ^ sw) << 3);
  const int cx1 = (((4+lk) ^ sw) << 3);
  float4v acc = {0.f,0.f,0.f,0.f};

  if (!flag){
    #pragma unroll
    for (int p = 0; p < 9; ++p){
      if (p < 8){
        ushort* dst = (p & 1) ? buf0 : buf1;
        glds16(aw + (size_t)(p+1)*16384,       dst);
        glds16(aw + (size_t)(p+1)*16384 + 512, dst + 512);
        asm volatile("s_waitcnt vmcnt(2)" ::: "memory");   // A(p) done
      } else {
        asm volatile("s_waitcnt vmcnt(0)" ::: "memory");
      }
      __builtin_amdgcn_sched_barrier(0);
      const ushort* ab = (p & 1) ? buf1 : buf0;
      short8v A0 = ldfrag(ab + lr*64 + cx0);
      short8v A1 = ldfrag(ab + lr*64 + cx1);
      int pinl = (p/3)*18 + lr + (p%3);
      const ushort* bl = &xsm[pinl*72 + lk*8];
      short8v BX0 = ldfrag(bl), BX1 = ldfrag(bl+32);
      acc = __builtin_amdgcn_mfma_f32_16x16x32_bf16(A0, BX0, acc, 0,0,0);
      acc = __builtin_amdgcn_mfma_f32_16x16x32_bf16(A1, BX1, acc, 0,0,0);
    }
  } else {
    // ---- cold pass 1 (hi halo staged above): Ahi*Bhi + Alo*Bhi ----
    #pragma unroll 1
    for (int p = 0; p < 9; ++p){
      glds16(aw  + (size_t)p*16384,       buf0);
      glds16(aw  + (size_t)p*16384 + 512, buf0 + 512);
      glds16(awl + (size_t)p*16384,       buf1);
      glds16(awl + (size_t)p*16384 + 512, buf1 + 512);
      asm volatile("s_waitcnt vmcnt(0)" ::: "memory");
      __builtin_amdgcn_sched_barrier(0);
      short8v A0  = ldfrag(buf0 + lr*64 + cx0);
      short8v A1  = ldfrag(buf0 + lr*64 + cx1);
      short8v Al0 = ldfrag(buf1 + lr*64 + cx0);
      short8v Al1 = ldfrag(buf1 + lr*64 + cx1);
      int pinl = (p/3)*18 + lr + (p%3);
      const ushort* bl = &xsm[pinl*72 + lk*8];
      short8v BX0 = ldfrag(bl), BX1 = ldfrag(bl+32);
      acc = __builtin_amdgcn_mfma_f32_16x16x32_bf16(A0,  BX0, acc, 0,0,0);
      acc = __builtin_amdgcn_mfma_f32_16x16x32_bf16(A1,  BX1, acc, 0,0,0);
      acc = __builtin_amdgcn_mfma_f32_16x16x32_bf16(Al0, BX0, acc, 0,0,0);
      acc = __builtin_amdgcn_mfma_f32_16x16x32_bf16(Al1, BX1, acc, 0,0,0);
      asm volatile("s_waitcnt lgkmcnt(0)" ::: "memory");
      __builtin_amdgcn_sched_barrier(0);
    }
    // ---- restage halo with LO data ----
    __syncthreads();
    for (int idx = tid; idx < 432; idx += 512){
      int slot = idx >> 3, c = idx & 7;
      int rr = slot / 18, xi = slot - rr*18;
      int gy = ytile - 1 + rr, gx2 = x0 - 1 + xi;
      bool valid = (gy >= 0) & (gy < 32) & (gx2 >= 0) & (gx2 < 32);
      int hp = gy*32 + gx2;
      uint4 v = valid ? *reinterpret_cast<const uint4*>(xlb + (size_t)hp*64 + c*8) : Z16;
      *reinterpret_cast<uint4*>(&xsm[slot*72 + c*8]) = v;
    }
    __syncthreads();
    // ---- cold pass 2: Ahi*Blo ----
    #pragma unroll 1
    for (int p = 0; p < 9; ++p){
      glds16(aw + (size_t)p*16384,       buf0);
      glds16(aw + (size_t)p*16384 + 512, buf0 + 512);
      asm volatile("s_waitcnt vmcnt(0)" ::: "memory");
      __builtin_amdgcn_sched_barrier(0);
      short8v A0 = ldfrag(buf0 + lr*64 + cx0);
      short8v A1 = ldfrag(buf0 + lr*64 + cx1);
      int pinl = (p/3)*18 + lr + (p%3);
      const ushort* bl = &xsm[pinl*72 + lk*8];
      short8v BXl0 = ldfrag(bl), BXl1 = ldfrag(bl+32);
      acc = __builtin_amdgcn_mfma_f32_16x16x32_bf16(A0, BXl0, acc, 0,0,0);
      acc = __builtin_amdgcn_mfma_f32_16x16x32_bf16(A1, BXl1, acc, 0,0,0);
      asm volatile("s_waitcnt lgkmcnt(0)" ::: "memory");
      __builtin_amdgcn_sched_barrier(0);
    }
  }

  {
    int cc = mh*32 + w*4 + lk;
    gxg[((size_t)tb*64 + cc)*1024 + px] = acc[2];
    ushort* go = gxo + ((size_t)tb*192 + cc*3)*1024 + px;
    go[0]    = f2bu(acc[0]);
    go[1024] = f2bu(acc[1]);
    go[2048] = f2bu(acc[3]);
  }
}

// ---------------------------------------------------------------------------
// FUSED conv (h-part) + peephole LSTM + 1x1 projections (R22-proven).
// grid (64 nt, 4 b) = 256 blocks, block 1024 = 16 waves.
// ---------------------------------------------------------------------------
__global__ __launch_bounds__(1024, 4) void k_convp(
  const int* __restrict__ flagp,
  const ushort* __restrict__ whah, const ushort* __restrict__ whal,
  const ushort* __restrict__ ht_hi, const ushort* __restrict__ ht_lo,
  const float* __restrict__ gxg, const ushort* __restrict__ gxo,
  const float* __restrict__ smalls, float* __restrict__ cst,
  const ushort* __restrict__ pwh, const ushort* __restrict__ pwl,
  const ushort* __restrict__ mth, const ushort* __restrict__ mtl,
  ushort* __restrict__ hnth, ushort* __restrict__ hntl,
  ushort* __restrict__ qb16, ushort* __restrict__ khb16, ushort* __restrict__ kmb16,
  ushort* __restrict__ vth16, ushort* __restrict__ vtm16, int t)
{
  __shared__ ushort albuf[16384];    // 16 waves x 1024 (in-place A refill)
  __shared__ ushort bsm[54*136];     // h halo hi+lo
  __shared__ ushort hbh[16*72];      // h-tile hi [px][cc], stride 72 (2-way)
  __shared__ ushort hbl[16*72];      // h-tile lo
  int nt = blockIdx.x, b = blockIdx.y;
  int tid = threadIdx.x;
  int flag = *flagp;
  int ytile = nt >> 1, x0 = (nt & 1) * 16;

  const ushort* hb  = ht_hi + (size_t)b*65536;
  const ushort* hlb = ht_lo + (size_t)b*65536;

  int w = tid >> 6, lane = tid & 63, lr = lane & 15, lk = lane >> 4;
  const ushort* aw  = whah + (size_t)(w*16)*64 + lane*8;   // + p*16384
  const ushort* awl = whal + (size_t)(w*16)*64 + lane*8;
  ushort* areg = albuf + w*1024;

  if (!flag){
    glds16(aw, areg);            // prefetch A(0), hides under halo staging
    glds16(aw + 512, areg + 512);
  }

  // acc init from precomputed X partials (loads issued early)
  int px = nt*16 + lr;
  int cc = w*4 + lk;
  int tb = b*8 + t;
  const ushort* go = gxo + ((size_t)tb*192 + cc*3)*1024 + px;
  float a0 = bu2f(go[0]);
  float a1 = bu2f(go[1024]);
  float a3 = bu2f(go[2048]);
  float a2 = gxg[((size_t)tb*64 + cc)*1024 + px];

  const uint4 Z16 = make_uint4(0,0,0,0);
  if (tid < 864){
    int slot = tid >> 4, c = tid & 15;
    int rr = slot / 18, xi = slot - rr*18;
    int gy = ytile - 1 + rr, gx2 = x0 - 1 + xi;
    bool valid = (gy >= 0) & (gy < 32) & (gx2 >= 0) & (gx2 < 32);
    int hpx = gy*32 + gx2;
    uint4 v = Z16;
    if (valid){
      if (c < 8) v = *reinterpret_cast<const uint4*>(hb  + (size_t)hpx*64 + c*8);
      else       v = *reinterpret_cast<const uint4*>(hlb + (size_t)hpx*64 + (c-8)*8);
    }
    *reinterpret_cast<uint4*>(&bsm[slot*136 + c*8]) = v;
  }
  __syncthreads();   // drains vmcnt+lgkmcnt -> A(0) resident, waits exact

  const int sw = lr & 7;
  const int c2n = ((lk ^ sw) << 3);
  const int c3n = (((4+lk) ^ sw) << 3);

  float4v acc = {a0, a1, a2, a3};

  if (!flag){
    #pragma unroll
    for (int p = 0; p < 9; ++p){
      if (p > 0){
        asm volatile("s_waitcnt vmcnt(0)" ::: "memory");
        __builtin_amdgcn_sched_barrier(0);
      }
      short8v A2 = ldfrag(areg + lr*64 + c2n);
      short8v A3 = ldfrag(areg + lr*64 + c3n);
      if (p < 8){
        asm volatile("s_waitcnt lgkmcnt(0)" ::: "memory");
        __builtin_amdgcn_sched_barrier(0);
        glds16(aw + (size_t)(p+1)*16384,       areg);
        glds16(aw + (size_t)(p+1)*16384 + 512, areg + 512);
        __builtin_amdgcn_sched_barrier(0);
      }
      int pinl = (p/3)*18 + lr + (p%3);
      const ushort* bl = &bsm[pinl*136 + lk*8];
      short8v BH0 = ldfrag(bl),    BH1 = ldfrag(bl+32);
      short8v BL0 = ldfrag(bl+64), BL1 = ldfrag(bl+96);
      acc = __builtin_amdgcn_mfma_f32_16x16x32_bf16(A2, BH0, acc, 0,0,0);
      acc = __builtin_amdgcn_mfma_f32_16x16x32_bf16(A3, BH1, acc, 0,0,0);
      acc = __builtin_amdgcn_mfma_f32_16x16x32_bf16(A2, BL0, acc, 0,0,0);
      acc = __builtin_amdgcn_mfma_f32_16x16x32_bf16(A3, BL1, acc, 0,0,0);
    }
  } else {
    // cold f32 path: in-place serial hi then lo per p
    #pragma unroll 1
    for (int p = 0; p < 9; ++p){
      glds16(aw + (size_t)p*16384,       areg);
      glds16(aw + (size_t)p*16384 + 512, areg + 512);
      asm volatile("s_waitcnt vmcnt(0)" ::: "memory");
      __builtin_amdgcn_sched_barrier(0);
      short8v A2 = ldfrag(areg + lr*64 + c2n);
      short8v A3 = ldfrag(areg + lr*64 + c3n);
      asm volatile("s_waitcnt lgkmcnt(0)" ::: "memory");
      __builtin_amdgcn_sched_barrier(0);
      glds16(awl + (size_t)p*16384,       areg);
      glds16(awl + (size_t)p*16384 + 512, areg + 512);
      asm volatile("s_waitcnt vmcnt(0)" ::: "memory");
      __builtin_amdgcn_sched_barrier(0);
      short8v Al2 = ldfrag(areg + lr*64 + c2n);
      short8v Al3 = ldfrag(areg + lr*64 + c3n);
      asm volatile("s_waitcnt lgkmcnt(0)" ::: "memory");
      __builtin_amdgcn_sched_barrier(0);
      int pinl = (p/3)*18 + lr + (p%3);
      const ushort* bl = &bsm[pinl*136 + lk*8];
      short8v BH0 = ldfrag(bl),    BH1 = ldfrag(bl+32);
      short8v BL0 = ldfrag(bl+64), BL1 = ldfrag(bl+96);
      acc = __builtin_amdgcn_mfma_f32_16x16x32_bf16(A2, BH0, acc, 0,0,0);
      acc = __builtin_amdgcn_mfma_f32_16x16x32_bf16(A3, BH1, acc, 0,0,0);
      acc = __builtin_amdgcn_mfma_f32_16x16x32_bf16(A2, BL0, acc, 0,0,0);
      acc = __builtin_amdgcn_mfma_f32_16x16x32_bf16(A3, BL1, acc, 0,0,0);
      acc = __builtin_amdgcn_mfma_f32_16x16x32_bf16(Al2, BH0, acc, 0,0,0);
      acc = __builtin_amdgcn_mfma_f32_16x16x32_bf16(Al3, BH1, acc, 0,0,0);
    }
  }

  // epilogue: peephole LSTM; h -> global hnT and LDS hbh/hbl
  {
    int wi = cc*1024 + px;
    size_t sidx = ((size_t)(b*64 + cc))*1024 + px;
    float cprev = cst[sidx];
    float ic = acc[0] + smalls[O_CB + cc];
    float fc = acc[1] + smalls[O_CB + 64 + cc];
    float gc = acc[2] + smalls[O_CB + 128 + cc];
    float oc = acc[3] + smalls[O_CB + 192 + cc];
    float ig = sigm(ic + smalls[O_WCI + wi]*cprev);
    float fg = sigm(fc + smalls[O_WCF + wi]*cprev);
    float cnew = fg*cprev + ig*tanhc(gc);
    float og = sigm(oc + smalls[O_WCO + wi]*cnew);
    cst[sidx] = cnew;
    float hv = og*tanhc(cnew);
    size_t tix = ((size_t)b*1024 + px)*64 + cc;
    ushort hh = f2bu(hv);
    ushort hl2 = f2bu(hv - bu2f(hh));
    hnth[tix] = hh;
    hntl[tix] = hl2;
    hbh[lr*72 + cc] = hh;
    hbl[lr*72 + cc] = hl2;
  }
  __syncthreads();

  // ---------------- proj phase: waves 0..10, one tile each ----------------
  if (w < 11){
    int tt = w;
    const float4v Z4 = {0.f,0.f,0.f,0.f};
    bool srcm = (tt == 2) || (tt >= 7);
    short8v b0, b1, bl0, bl1;
    if (srcm){
      size_t bb = ((size_t)b*1024 + nt*16 + lr)*64 + lk*8;
      b0  = ldfrag(mth + bb);  b1  = ldfrag(mth + bb + 32);
      bl0 = ldfrag(mtl + bb);  bl1 = ldfrag(mtl + bb + 32);
    } else {
      b0  = ldfrag(&hbh[lr*72 + lk*8]);  b1  = ldfrag(&hbh[lr*72 + 32 + lk*8]);
      bl0 = ldfrag(&hbl[lr*72 + lk*8]);  bl1 = ldfrag(&hbl[lr*72 + 32 + lk*8]);
    }
    const ushort* ar = pwh + (size_t)(tt*16 + lr)*64 + lk*8;
    short8v pa0 = ldfrag(ar), pa1 = ldfrag(ar + 32);
    float4v d = Z4;
    d = __builtin_amdgcn_mfma_f32_16x16x32_bf16(pa0, b0,  d, 0,0,0);
    d = __builtin_amdgcn_mfma_f32_16x16x32_bf16(pa1, b1,  d, 0,0,0);
    d = __builtin_amdgcn_mfma_f32_16x16x32_bf16(pa0, bl0, d, 0,0,0);
    d = __builtin_amdgcn_mfma_f32_16x16x32_bf16(pa1, bl1, d, 0,0,0);
    if (flag){
      const ushort* arl = pwl + (size_t)(tt*16 + lr)*64 + lk*8;
      short8v pal0 = ldfrag(arl), pal1 = ldfrag(arl + 32);
      d = __builtin_amdgcn_mfma_f32_16x16x32_bf16(pal0, b0, d, 0,0,0);
      d = __builtin_amdgcn_mfma_f32_16x16x32_bf16(pal1, b1, d, 0,0,0);
    }
    int n = nt*16 + lr;
    int boff = (tt==0) ? O_QB : (tt==1) ? O_KB : (tt==2) ? O_K2B
             : (tt<7) ? (O_VB + (tt-3)*16) : (O_V2B + (tt-7)*16);
    if (tt < 3){
      ushort* base = (tt==0) ? qb16 : (tt==1) ? khb16 : kmb16;
      ushort u[4];
      #pragma unroll
      for (int q = 0; q < 4; ++q)
        u[q] = f2bu(d[q] + smalls[boff + lk*4 + q]);
      *reinterpret_cast<uint2*>(&base[((size_t)b*1024 + n)*32 + lk*4]) =
        make_uint2((unsigned)u[0] | ((unsigned)u[1]<<16),
                   (unsigned)u[2] | ((unsigned)u[3]<<16));
    } else {
      ushort* base = (tt<7) ? vth16 : vtm16;
      int cc0 = ((tt<7) ? (tt-3) : (tt-7))*16 + lk*4;
      #pragma unroll
      for (int q = 0; q < 4; ++q)
        base[((size_t)b*64 + cc0 + q)*1024 + n] = f2bu(d[q] + smalls[boff + lk*4 + q]);
    }
  }
}

// ---------------------------------------------------------------------------
// FUSED: MFMA flash attention (both branches) + MFMA zcomb GEMMs + gating —
// R23-proven (double-buffered P-tile, one barrier per mc-chunk).
// ---------------------------------------------------------------------------
__global__ __launch_bounds__(512) void k_fattz(
  const ushort* __restrict__ qb16, const ushort* __restrict__ khb16,
  const ushort* __restrict__ kmb16, const ushort* __restrict__ vth16,
  const ushort* __restrict__ vtm16,
  const ushort* __restrict__ hnth, const ushort* __restrict__ hntl,
  const float* __restrict__ smalls,
  const ushort* __restrict__ zw16h, const ushort* __restrict__ zw16l,
  const ushort* __restrict__ mw16h, const ushort* __restrict__ mw16l,
  const int* __restrict__ flagp,
  float* __restrict__ mst, ushort* __restrict__ mth, ushort* __restrict__ mtl,
  ushort* __restrict__ hth, ushort* __restrict__ htl,
  void* __restrict__ outraw, int t)
{
  __shared__ __align__(16) unsigned char poolA[34816]; // es[2br][2buf] | zb | ho+mn
  __shared__ __align__(16) ushort ztbh[16*136];
  __shared__ __align__(16) ushort ztbl[16*136];
  __shared__ float cb[192*17];
  __shared__ float ml[64*17];
  __shared__ float rs_s[2][4][16];

  ushort* es   = (ushort*)poolA;              // [br][buf][16][272]
  ushort* zbh  = (ushort*)poolA;              // aliases es after attn
  ushort* zbl  = (ushort*)(poolA + 8704);
  float*  ho_s = (float*)poolA;
  float*  mn_s = (float*)(poolA + 4352);

  int nt = blockIdx.x, b = blockIdx.y;
  int n0 = nt*16;
  int tid = threadIdx.x;
  int w = tid >> 6, lane = tid & 63, lr = lane & 15, lk = lane >> 4;
  int br = w >> 2, wq = w & 3;
  int flag = *flagp;
  const float4v Z4 = {0.f,0.f,0.f,0.f};

  const ushort* kb = (br ? kmb16 : khb16) + (size_t)b*32768;
  const ushort* vt = (br ? vtm16 : vth16) + (size_t)b*65536;
  const ushort* qp = qb16 + (size_t)b*32768;

  for (int idx = tid; idx < 1024; idx += 512){
    int ch = idx >> 4, pp = idx & 15;
    ml[ch*17+pp] = mst[((size_t)b*64 + ch)*1024 + n0 + pp];
  }

  short8v qf = ldfrag(qp + (size_t)(n0 + lr)*32 + lk*8);

  float4v acc[2];
  acc[0]=Z4; acc[1]=Z4;
  float rsum = 0.f;

  #pragma unroll 1
  for (int mc = 0; mc < 4; ++mc){
    ushort* esb = es + (br*2 + (mc & 1))*4352;
    int mbase = mc*256 + wq*64;
    #pragma unroll
    for (int tau = 0; tau < 4; ++tau){
      short8v af = ldfrag(kb + (size_t)(mbase + tau*16 + lr)*32 + lk*8);
      float4v d = __builtin_amdgcn_mfma_f32_16x16x32_bf16(af, qf, Z4, 0,0,0);
      ushort u0 = f2bu(__expf(fminf(d[0], 60.f)));
      ushort u1 = f2bu(__expf(fminf(d[1], 60.f)));
      ushort u2 = f2bu(__expf(fminf(d[2], 60.f)));
      ushort u3 = f2bu(__expf(fminf(d[3], 60.f)));
      rsum += (bu2f(u0) + bu2f(u1)) + (bu2f(u2) + bu2f(u3));
      unsigned lo = (unsigned)u0 | ((unsigned)u1 << 16);
      unsigned hi = (unsigned)u2 | ((unsigned)u3 << 16);
      *reinterpret_cast<uint2*>(&esb[lr*272 + wq*64 + tau*16 + lk*4]) = make_uint2(lo, hi);
    }
    __syncthreads();
    #pragma unroll
    for (int ks = 0; ks < 8; ++ks){
      short8v av = ldfrag(vt + (size_t)(wq*16 + lr)*1024 + mc*256 + ks*32 + lk*8);
      short8v bv = ldfrag(&esb[lr*272 + ks*32 + lk*8]);
      acc[ks & 1] = __builtin_amdgcn_mfma_f32_16x16x32_bf16(av, bv, acc[ks & 1], 0,0,0);
    }
    // no trailing barrier: next mc writes the ALTERNATE buffer; the
    // mc+1 barrier orders those reads before mc+2's overwrite.
  }

  {
    float r = rsum;
    r += __shfl_xor(r, 16);
    r += __shfl_xor(r, 32);
    if (lane < 16) rs_s[br][wq][lr] = r;
  }
  __syncthreads();   // all PV reads done -> es region reusable as zb
  {
    float rinv = 1.0f / (rs_s[br][0][lr] + rs_s[br][1][lr] + rs_s[br][2][lr] + rs_s[br][3][lr]);
    int ch0 = br*64 + wq*16 + lk*4;
    ushort uh[4], ul[4];
    #pragma unroll
    for (int r = 0; r < 4; ++r){
      float z = (acc[0][r] + acc[1][r])*rinv;
      uh[r] = f2bu(z);
      ul[r] = f2bu(z - bu2f(uh[r]));
    }
    *reinterpret_cast<uint2*>(&zbh[lr*136 + ch0]) =
      make_uint2((unsigned)uh[0] | ((unsigned)uh[1]<<16), (unsigned)uh[2] | ((unsigned)uh[3]<<16));
    *reinterpret_cast<uint2*>(&zbl[lr*136 + ch0]) =
      make_uint2((unsigned)ul[0] | ((unsigned)ul[1]<<16), (unsigned)ul[2] | ((unsigned)ul[3]<<16));
  }
  __syncthreads();

  // ---------------- GEMM1: zt = z_w @ z + z_b ----------------
  {
    float4v zacc = Z4;
    if (!flag){
      #pragma unroll
      for (int kf = 0; kf < 4; ++kf){
        short8v a  = ldfrag(zw16h + (size_t)(w*16 + lr)*128 + kf*32 + lk*8);
        short8v bh = ldfrag(&zbh[lr*136 + kf*32 + lk*8]);
        short8v bl = ldfrag(&zbl[lr*136 + kf*32 + lk*8]);
        zacc = __builtin_amdgcn_mfma_f32_16x16x32_bf16(a, bh, zacc, 0,0,0);
        zacc = __builtin_amdgcn_mfma_f32_16x16x32_bf16(a, bl, zacc, 0,0,0);
      }
    } else {
      #pragma unroll
      for (int kf = 0; kf < 4; ++kf){
        short8v a  = ldfrag(zw16h + (size_t)(w*16 + lr)*128 + kf*32 + lk*8);
        short8v al = ldfrag(zw16l + (size_t)(w*16 + lr)*128 + kf*32 + lk*8);
        short8v bh = ldfrag(&zbh[lr*136 + kf*32 + lk*8]);
        short8v bl = ldfrag(&zbl[lr*136 + kf*32 + lk*8]);
        zacc = __builtin_amdgcn_mfma_f32_16x16x32_bf16(a,  bh, zacc, 0,0,0);
        zacc = __builtin_amdgcn_mfma_f32_16x16x32_bf16(a,  bl, zacc, 0,0,0);
        zacc = __builtin_amdgcn_mfma_f32_16x16x32_bf16(al, bh, zacc, 0,0,0);
      }
    }
    int r0 = w*16 + lk*4;
    ushort th[4], tl[4];
    #pragma unroll
    for (int q = 0; q < 4; ++q){
      float ztv = zacc[q] + smalls[O_ZB + r0 + q];
      th[q] = f2bu(ztv);
      tl[q] = f2bu(ztv - bu2f(th[q]));
    }
    *reinterpret_cast<uint2*>(&ztbh[lr*136 + r0]) =
      make_uint2((unsigned)th[0] | ((unsigned)th[1]<<16), (unsigned)th[2] | ((unsigned)th[3]<<16));
    *reinterpret_cast<uint2*>(&ztbl[lr*136 + r0]) =
      make_uint2((unsigned)tl[0] | ((unsigned)tl[1]<<16), (unsigned)tl[2] | ((unsigned)tl[3]<<16));
  }
  __syncthreads();

  // ------- GEMM2: comb = m_w @ [zt; h] + m_b -------
  const ushort* hrow  = hnth + ((size_t)b*1024 + n0 + lr)*64;
  const ushort* hrowl = hntl + ((size_t)b*1024 + n0 + lr)*64;
  #pragma unroll
  for (int mi = 0; mi < 2; ++mi){
    if (mi == 1 && w >= 4) break;
    int mf = (mi == 0) ? w : (w + 8);
    float4v cacc = Z4;
    const ushort* arow  = mw16h + (size_t)(mf*16 + lr)*192;
    const ushort* arowl = mw16l + (size_t)(mf*16 + lr)*192;
    if (!flag){
      #pragma unroll
      for (int kf = 0; kf < 4; ++kf){
        short8v a  = ldfrag(arow + kf*32 + lk*8);
        short8v bh = ldfrag(&ztbh[lr*136 + kf*32 + lk*8]);
        short8v bl = ldfrag(&ztbl[lr*136 + kf*32 + lk*8]);
        cacc = __builtin_amdgcn_mfma_f32_16x16x32_bf16(a, bh, cacc, 0,0,0);
        cacc = __builtin_amdgcn_mfma_f32_16x16x32_bf16(a, bl, cacc, 0,0,0);
      }
      #pragma unroll
      for (int kf = 0; kf < 2; ++kf){
        short8v a  = ldfrag(arow + 128 + kf*32 + lk*8);
        short8v bh = ldfrag(hrow + kf*32 + lk*8);
        short8v bl = ldfrag(hrowl + kf*32 + lk*8);
        cacc = __builtin_amdgcn_mfma_f32_16x16x32_bf16(a, bh, cacc, 0,0,0);
        cacc = __builtin_amdgcn_mfma_f32_16x16x32_bf16(a, bl, cacc, 0,0,0);
      }
    } else {
      #pragma unroll
      for (int kf = 0; kf < 4; ++kf){
        short8v a  = ldfrag(arow + kf*32 + lk*8);
        short8v al = ldfrag(arowl + kf*32 + lk*8);
        short8v bh = ldfrag(&ztbh[lr*136 + kf*32 + lk*8]);
        short8v bl = ldfrag(&ztbl[lr*136 + kf*32 + lk*8]);
        cacc = __builtin_amdgcn_mfma_f32_16x16x32_bf16(a,  bh, cacc, 0,0,0);
        cacc = __builtin_amdgcn_mfma_f32_16x16x32_bf16(a,  bl, cacc, 0,0,0);
        cacc = __builtin_amdgcn_mfma_f32_16x16x32_bf16(al, bh, cacc, 0,0,0);
      }
      #pragma unroll
      for (int kf = 0; kf < 2; ++kf){
        short8v a  = ldfrag(arow + 128 + kf*32 + lk*8);
        short8v al = ldfrag(arowl + 128 + kf*32 + lk*8);
        short8v bh = ldfrag(hrow + kf*32 + lk*8);
        short8v bl = ldfrag(hrowl + kf*32 + lk*8);
        cacc = __builtin_amdgcn_mfma_f32_16x16x32_bf16(a,  bh, cacc, 0,0,0);
        cacc = __builtin_amdgcn_mfma_f32_16x16x32_bf16(a,  bl, cacc, 0,0,0);
        cacc = __builtin_amdgcn_mfma_f32_16x16x32_bf16(al, bh, cacc, 0,0,0);
      }
    }
    int r0 = mf*16 + lk*4;
    #pragma unroll
    for (int q = 0; q < 4; ++q)
      cb[(r0+q)*17 + lr] = cacc[q] + smalls[O_MB + r0 + q];
  }
  __syncthreads();

  // ---------------- gating ----------------
  {
    int px = tid >> 5, lr2 = tid & 31;
    #pragma unroll
    for (int j = 0; j < 2; ++j){
      int ch = lr2 + 32*j;
      float mo = cb[ch*17 + px];
      float mg = cb[(64+ch)*17 + px];
      float mi = cb[(128+ch)*17 + px];
      float mold = ml[ch*17 + px];
      float gi = sigm(mi);
      float mnew = (1.0f-gi)*mold + gi*tanhc(mg);
      float ho = sigm(mo)*mnew;
      ho_s[ch*17+px] = ho;
      mn_s[ch*17+px] = mnew;
    }
  }
  __syncthreads();
  for (int idx = tid; idx < 1024; idx += 512){
    int ch = idx >> 4, pp = idx & 15;
    int n = n0 + pp;
    size_t gidx = ((size_t)b*64 + ch)*1024 + n;
    float mn = mn_s[ch*17+pp];
    mst[gidx] = mn;
    float ho = ho_s[ch*17+pp];
    size_t tix = ((size_t)b*1024 + n)*64 + ch;
    ushort hb_ = f2bu(ho);
    hth[tix] = hb_;
    htl[tix] = f2bu(ho - bu2f(hb_));
    ushort mh_ = f2bu(mn);
    mth[tix] = mh_;
    mtl[tix] = f2bu(mn - bu2f(mh_));
    size_t oidx = ((size_t)(b*64+ch)*8 + t)*1024 + n;
    if (flag) ((float*)outraw)[oidx] = ho;
    else      ((bf16*)outraw)[oidx] = __float2bfloat16(ho);
  }
}

extern "C" void kernel_launch(void* const* d_in, const int* in_sizes, int n_in,
                              void* d_out, int out_size, void* d_ws, size_t ws_size,
                              hipStream_t stream)
{
  float* ws = (float*)d_ws;
  int* flag = (int*)(ws + WS_FLAG);
  float* c    = ws + WS_C;
  float* m    = ws + WS_M;
  float* gxg  = ws + WS_GXG;
  ushort* gxo   = (ushort*)(ws + WS_GXO);
  ushort* qb16  = (ushort*)(ws + WS_QB16);
  ushort* khb16 = (ushort*)(ws + WS_KHB16);
  ushort* kmb16 = (ushort*)(ws + WS_KMB16);
  ushort* vth16 = (ushort*)(ws + WS_VTH16);
  ushort* vtm16 = (ushort*)(ws + WS_VTM16);
  ushort* mth   = (ushort*)(ws + WS_MTH);
  ushort* mtl   = (ushort*)(ws + WS_MTL);
  ushort* hnth  = (ushort*)(ws + WS_HNTH);
  ushort* hntl  = (ushort*)(ws + WS_HNTL);
  ushort* zw16h = (ushort*)(ws + WS_ZW16H);
  ushort* zw16l = (ushort*)(ws + WS_ZW16L);
  ushort* mw16h = (ushort*)(ws + WS_MW16H);
  ushort* mw16l = (ushort*)(ws + WS_MW16L);
  ushort* wxah  = (ushort*)(ws + WS_WXAH);
  ushort* wxal  = (ushort*)(ws + WS_WXAL);
  ushort* whah  = (ushort*)(ws + WS_WHAH);
  ushort* whal  = (ushort*)(ws + WS_WHAL);
  ushort* xt_hi = (ushort*)(ws + WS_XTHI);
  ushort* xt_lo = (ushort*)(ws + WS_XTLO);
  ushort* ht_hi = (ushort*)(ws + WS_HTHI);
  ushort* ht_lo = (ushort*)(ws + WS_HTLO);
  ushort* pwh   = (ushort*)(ws + WS_PWH);
  ushort* pwl   = (ushort*)(ws + WS_PWL);

  k_probe<<<1, 256, 0, stream>>>((const unsigned int*)d_in[0], flag);
  P18 pk;
  for (int i = 0; i < 18; ++i) pk.p[i] = d_in[2 + i];
  k_wconv<<<dim3(64,18), 256, 0, stream>>>(pk, flag, ws);
  k_init<<<3072, 256, 0, stream>>>(d_in[1], flag, ws);
  k_xt<<<dim3(16,32), 256, 0, stream>>>(d_in[0], flag, ws);
  k_wtrans<<<144, 256, 0, stream>>>(ws);
  k_convx<<<dim3(64,2,32), 512, 0, stream>>>(flag, wxah, wxal, xt_hi, xt_lo, gxg, gxo);

  for (int t = 0; t < 8; ++t){
    k_convp<<<dim3(64,4), 1024, 0, stream>>>(flag, whah, whal, ht_hi, ht_lo,
                                             gxg, gxo, ws, c, pwh, pwl, mth, mtl,
                                             hnth, hntl, qb16, khb16, kmb16,
                                             vth16, vtm16, t);
    k_fattz<<<dim3(64,4), 512, 0, stream>>>(qb16, khb16, kmb16, vth16, vtm16,
                                            hnth, hntl, ws, zw16h, zw16l, mw16h, mw16l,
                                            flag, m, mth, mtl, ht_hi, ht_lo, d_out, t);
  }
  (void)in_sizes; (void)n_in; (void)out_size; (void)ws_size;
}

// Round 25
// 389.848 us; speedup vs baseline: 1.0808x; 1.0808x over previous
//
#include <hip/hip_runtime.h>
#include <hip/hip_bf16.h>

typedef __hip_bfloat16 bf16;
typedef unsigned short ushort;
typedef __attribute__((ext_vector_type(8))) short short8v;   // 8 bf16 = 4 VGPR
typedef __attribute__((ext_vector_type(4))) float float4v;

__device__ __forceinline__ float b2f(bf16 v){ return __bfloat162float(v); }
__device__ __forceinline__ float sigm(float x){ return 1.0f/(1.0f+__expf(-x)); }
__device__ __forceinline__ float tanhc(float x){
  x = fminf(15.0f, fmaxf(-15.0f, x));
  float e = __expf(2.0f*x);
  return (e-1.0f)/(e+1.0f);
}
__device__ __forceinline__ ushort f2bu(float f){
  bf16 h = __float2bfloat16(f); return *reinterpret_cast<ushort*>(&h);
}
__device__ __forceinline__ float bu2f(ushort u){
  return __uint_as_float(((unsigned)u)<<16);
}
__device__ __forceinline__ short8v ldfrag(const ushort* p){
  return *reinterpret_cast<const short8v*>(p);
}
// direct global->LDS DMA, 16B per lane; lds dst = uniform base + lane*16
__device__ __forceinline__ void glds16(const ushort* g, ushort* l){
  __builtin_amdgcn_global_load_lds(
    (const __attribute__((address_space(1))) unsigned int*)g,
    (__attribute__((address_space(3))) unsigned int*)l, 16, 0, 0);
}

// ---------------------------------------------------------------------------
// ws layout (float offsets)
// ---------------------------------------------------------------------------
#define WS_SMALL   0
#define WS_FLAG    262144
#define WS_ZROW    262160
#define WS_H       262208
#define WS_C       524352
#define WS_M       786496
#define WS_QB16    1310784
#define WS_KHB16   1376320
#define WS_KMB16   1441856
#define WS_VTH16   1507392
#define WS_VTM16   1638464
#define WS_MTH     1769536
#define WS_MTL     1900608
#define WS_HNTH    2031680
#define WS_HNTL    2162752
#define WS_ZW16H   2293824
#define WS_ZW16L   2302016
#define WS_MW16H   2310208
#define WS_MW16L   2328640
#define WS_WXAH    2347072     // 73728 f (147456 ushort) X weights hi
#define WS_WHAH    2420800     // 73728 f h weights hi
#define WS_WXAL    2494528     // 73728 f X weights lo
#define WS_WHAL    2568256     // 73728 f h weights lo
#define WS_XTHI    2641984
#define WS_XTLO    3690560
#define WS_HTHI    4739136
#define WS_HTLO    4870208
#define WS_PWH     5001280
#define WS_PWL     5006912
#define WS_GXG     5012544     // 2097152 f32: g-gate X-partial [bt][64cc][1024]
#define WS_GXO     7109696     // 6291456 ushort: i/f/o X-partials [bt][192][1024]
// total 10255424 f = 41.0 MB (ws known >= 45.2 MB from R2)
// small-weight offsets inside WS_SMALL
#define O_CB    0
#define O_WCI   256
#define O_WCF   65792
#define O_WCO   131328
#define O_QW    196864
#define O_QB    197888
#define O_KW    197904
#define O_KB    198928
#define O_K2W   198944
#define O_K2B   199968
#define O_VW    199984
#define O_VB    204080
#define O_V2W   204144
#define O_V2B   208240
#define O_ZW    208304
#define O_ZB    224688
#define O_MW    224816
#define O_MB    261680

// ---------------------------------------------------------------------------
// dtype probe (f32 vs bf16 input data)
// ---------------------------------------------------------------------------
__global__ void k_probe(const unsigned int* __restrict__ Xu, int* __restrict__ flag){
  __shared__ int cnt;
  if (threadIdx.x == 0) cnt = 0;
  __syncthreads();
  unsigned int u = Xu[threadIdx.x];
  float f = __uint_as_float((u & 0xffffu) << 16);
  int bad = (fabsf(f) <= 1e4f) ? 0 : 1;
  atomicAdd(&cnt, bad);
  __syncthreads();
  if (threadIdx.x == 0) *flag = (cnt > 16) ? 1 : 0;
}

// ---------------------------------------------------------------------------
// convert the 18 small inputs into f32 copies in ws
// ---------------------------------------------------------------------------
struct P18 { const void* p[18]; };

__global__ __launch_bounds__(256) void k_wconv(P18 pk, const int* __restrict__ flagp,
                                               float* __restrict__ dst){
  const int ns[18]   = {256,65536,65536,65536,1024,16,1024,16,1024,16,
                        4096,64,4096,64,16384,128,36864,192};
  const int offs[18] = {O_CB,O_WCI,O_WCF,O_WCO,O_QW,O_QB,O_KW,O_KB,O_K2W,O_K2B,
                        O_VW,O_VB,O_V2W,O_V2B,O_ZW,O_ZB,O_MW,O_MB};
  int y = blockIdx.y;
  int n = ns[y];
  int flag = *flagp;
  const void* src = pk.p[y];
  for (int i = blockIdx.x*256 + threadIdx.x; i < n; i += gridDim.x*256){
    float v = flag ? ((const float*)src)[i] : b2f(((const bf16*)src)[i]);
    dst[offs[y] + i] = v;
  }
}

// bf16 hi/lo copies: z_w (128x128), m_w (192x192), proj weights [176][64]
__global__ __launch_bounds__(256) void k_wtrans(float* __restrict__ ws){
  int i = blockIdx.x*256 + threadIdx.x;
  if (i < 16384){
    float f = ws[O_ZW + i];
    ushort h = f2bu(f);
    ((ushort*)(ws + WS_ZW16H))[i] = h;
    ((ushort*)(ws + WS_ZW16L))[i] = f2bu(f - bu2f(h));
  }
  if (i < 36864){
    float f = ws[O_MW + i];
    ushort h = f2bu(f);
    ((ushort*)(ws + WS_MW16H))[i] = h;
    ((ushort*)(ws + WS_MW16L))[i] = f2bu(f - bu2f(h));
  }
  if (i < 11264){
    int r = i >> 6, k = i & 63;
    float f;
    if (r < 16)       f = ws[O_QW  + r*64 + k];
    else if (r < 32)  f = ws[O_KW  + (r-16)*64 + k];
    else if (r < 48)  f = ws[O_K2W + (r-32)*64 + k];
    else if (r < 112) f = ws[O_VW  + (r-48)*64 + k];
    else              f = ws[O_V2W + (r-112)*64 + k];
    ushort h = f2bu(f);
    ((ushort*)(ws + WS_PWH))[i] = h;
    ((ushort*)(ws + WS_PWL))[i] = f2bu(f - bu2f(h));
  }
}

// ---------------------------------------------------------------------------
// init: zero states + hT + mT + q/k pad; split conv weights into X-only
// (wxa) and h-only (wha) layouts, both chunk-swizzled c ^= (mm&7) over
// 8 chunks of 8 ushort per 64-ci row.
// ---------------------------------------------------------------------------
__global__ __launch_bounds__(256) void k_init(const void* __restrict__ conv_w,
                                              const int* __restrict__ flagp,
                                              float* __restrict__ ws){
  int i = blockIdx.x*256 + threadIdx.x;
  int flag = *flagp;
  if (i < 786432) ws[WS_H + i] = 0.0f;
  if (i < 32) ws[WS_ZROW + i] = 0.0f;
  if (i < 196608) ((unsigned*)(ws + WS_QB16))[i] = 0u;   // qb/kh/km incl. pad
  if (i < 294912){
    int ci = i & 127;
    int j = i >> 7;           // j = p*256 + mm
    int mm = j & 255, p = j >> 8;
    int cc = mm >> 2, g = mm & 3;
    int si = ((g*64 + cc)*128 + ci)*9 + p;
    float f;
    ushort hi, lo = 0;
    if (flag){
      f = ((const float*)conv_w)[si];
      hi = f2bu(f);
      lo = f2bu(f - bu2f(hi));
    } else {
      hi = ((const ushort*)conv_w)[si];
    }
    if (ci < 64){
      int di = (j << 6) + ((((ci >> 3) ^ (mm & 7)) << 3) | (ci & 7));
      ((ushort*)(ws + WS_WXAH))[di] = hi;
      ((ushort*)(ws + WS_WXAL))[di] = lo;
    } else {
      int c2 = ci - 64;
      int di = (j << 6) + ((((c2 >> 3) ^ (mm & 7)) << 3) | (c2 & 7));
      ((ushort*)(ws + WS_WHAH))[di] = hi;
      ((ushort*)(ws + WS_WHAL))[di] = lo;
    }
  }
  if (i < 131072){
    ((unsigned*)(ws + WS_HTHI))[i] = 0u;
    ((unsigned*)(ws + WS_HTLO))[i] = 0u;
    ((unsigned*)(ws + WS_MTH))[i] = 0u;
    ((unsigned*)(ws + WS_MTL))[i] = 0u;
  }
}

// ---------------------------------------------------------------------------
// X transpose: XT[b][t][px][ci]
// ---------------------------------------------------------------------------
__global__ __launch_bounds__(256) void k_xt(const void* __restrict__ Xraw,
                                            const int* __restrict__ flagp,
                                            float* __restrict__ ws){
  __shared__ ushort hi_s[64][66];
  __shared__ ushort lo_s[64][66];
  int pt = blockIdx.x, s = blockIdx.y;
  int b = s >> 3, t = s & 7;
  int flag = *flagp;
  int tid = threadIdx.x;
  for (int k = 0; k < 16; ++k){
    int idx = tid + k*256;
    int ci = idx >> 6, pxl = idx & 63;
    size_t si = ((size_t)(b*64 + ci)*8 + t)*1024 + pt*64 + pxl;
    if (flag){
      float f = ((const float*)Xraw)[si];
      ushort h = f2bu(f);
      hi_s[pxl][ci] = h;
      lo_s[pxl][ci] = f2bu(f - bu2f(h));
    } else {
      hi_s[pxl][ci] = ((const ushort*)Xraw)[si];
    }
  }
  __syncthreads();
  ushort* xh = (ushort*)(ws + WS_XTHI) + ((size_t)s*1024 + pt*64)*64;
  ushort* xl = (ushort*)(ws + WS_XTLO) + ((size_t)s*1024 + pt*64)*64;
  for (int k = 0; k < 16; ++k){
    int idx = tid + k*256;
    int pxl = idx >> 6, ci = idx & 63;
    xh[pxl*64 + ci] = hi_s[pxl][ci];
    if (flag) xl[pxl*64 + ci] = lo_s[pxl][ci];
  }
}

// ---------------------------------------------------------------------------
// k_convx: time-invariant X-part of the conv gates for ALL (b,t) at once.
// grid (64 nt, 2 mh, 32 bt) = 4096 blocks, block 512 = 8 waves.
// R18/R23-proven structure. CLOSED: R19 counted-vmcnt, R20 4x-reuse, and
// R24 occupancy-neutral dbuf all regressed (R24: L2 write-combining broke,
// WRITE_SIZE 20->53 MB). Do not touch.
// ---------------------------------------------------------------------------
__global__ __launch_bounds__(512, 4) void k_convx(
  const int* __restrict__ flagp,
  const ushort* __restrict__ wxah, const ushort* __restrict__ wxal,
  const ushort* __restrict__ xt_hi, const ushort* __restrict__ xt_lo,
  float* __restrict__ gxg, ushort* __restrict__ gxo)
{
  __shared__ ushort xabuf[8192];     // 8 waves x 1024 ushort (A slices)
  __shared__ ushort xsm[54*136];     // X halo (hi + optional lo)
  int nt = blockIdx.x, mh = blockIdx.y, tb = blockIdx.z;
  int tid = threadIdx.x;
  int flag = *flagp;
  int ytile = nt >> 1, x0 = (nt & 1) * 16;
  const ushort* xb  = xt_hi + (size_t)tb*65536;
  const ushort* xlb = xt_lo + (size_t)tb*65536;
  int w = tid >> 6, lane = tid & 63, lr = lane & 15, lk = lane >> 4;
  const ushort* aw  = wxah + (size_t)(mh*128 + w*16)*64 + lane*8;  // + p*16384
  const ushort* awl = wxal + (size_t)(mh*128 + w*16)*64 + lane*8;
  ushort* areg = xabuf + w*1024;

  const uint4 Z16 = make_uint4(0,0,0,0);
  for (int idx = tid; idx < 864; idx += 512){
    int slot = idx >> 4, c = idx & 15;
    int rr = slot / 18, xi = slot - rr*18;
    int gy = ytile - 1 + rr, gx2 = x0 - 1 + xi;
    bool valid = (gy >= 0) & (gy < 32) & (gx2 >= 0) & (gx2 < 32);
    int px = gy*32 + gx2;
    uint4 v = Z16;
    if (valid){
      if (c < 8)       v = *reinterpret_cast<const uint4*>(xb  + (size_t)px*64 + c*8);
      else if (flag)   v = *reinterpret_cast<const uint4*>(xlb + (size_t)px*64 + (c-8)*8);
    }
    *reinterpret_cast<uint4*>(&xsm[slot*136 + c*8]) = v;
  }
  __syncthreads();

  int px = nt*16 + lr;
  int sw = lr & 7;
  const int cx0 = ((lk ^ sw) << 3);
  const int cx1 = (((4+lk) ^ sw) << 3);
  float4v acc = {0.f,0.f,0.f,0.f};

  #pragma unroll 1
  for (int p = 0; p < 9; ++p){
    glds16(aw + (size_t)p*16384,       areg);
    glds16(aw + (size_t)p*16384 + 512, areg + 512);
    asm volatile("s_waitcnt vmcnt(0)" ::: "memory");
    __builtin_amdgcn_sched_barrier(0);
    short8v A0 = ldfrag(areg + lr*64 + cx0);
    short8v A1 = ldfrag(areg + lr*64 + cx1);
    int pinl = (p/3)*18 + lr + (p%3);
    const ushort* bl = &xsm[pinl*136 + lk*8];
    short8v BX0 = ldfrag(bl), BX1 = ldfrag(bl+32);
    acc = __builtin_amdgcn_mfma_f32_16x16x32_bf16(A0, BX0, acc, 0,0,0);
    acc = __builtin_amdgcn_mfma_f32_16x16x32_bf16(A1, BX1, acc, 0,0,0);
    if (flag){
      short8v BXl0 = ldfrag(bl+64), BXl1 = ldfrag(bl+96);
      acc = __builtin_amdgcn_mfma_f32_16x16x32_bf16(A0, BXl0, acc, 0,0,0);
      acc = __builtin_amdgcn_mfma_f32_16x16x32_bf16(A1, BXl1, acc, 0,0,0);
      asm volatile("s_waitcnt lgkmcnt(0)" ::: "memory");
      __builtin_amdgcn_sched_barrier(0);
      glds16(awl + (size_t)p*16384,       areg);
      glds16(awl + (size_t)p*16384 + 512, areg + 512);
      asm volatile("s_waitcnt vmcnt(0)" ::: "memory");
      __builtin_amdgcn_sched_barrier(0);
      short8v Al0 = ldfrag(areg + lr*64 + cx0);
      short8v Al1 = ldfrag(areg + lr*64 + cx1);
      acc = __builtin_amdgcn_mfma_f32_16x16x32_bf16(Al0, BX0, acc, 0,0,0);
      acc = __builtin_amdgcn_mfma_f32_16x16x32_bf16(Al1, BX1, acc, 0,0,0);
      asm volatile("s_waitcnt lgkmcnt(0)" ::: "memory");
      __builtin_amdgcn_sched_barrier(0);
    } else {
      asm volatile("s_waitcnt lgkmcnt(0)" ::: "memory");   // areg reusable
      __builtin_amdgcn_sched_barrier(0);
    }
  }

  {
    int cc = mh*32 + w*4 + lk;
    gxg[((size_t)tb*64 + cc)*1024 + px] = acc[2];
    ushort* go = gxo + ((size_t)tb*192 + cc*3)*1024 + px;
    go[0]    = f2bu(acc[0]);
    go[1024] = f2bu(acc[1]);
    go[2048] = f2bu(acc[3]);
  }
}

// ---------------------------------------------------------------------------
// FUSED conv (h-part) + peephole LSTM + 1x1 projections (R22-proven).
// grid (64 nt, 4 b) = 256 blocks, block 1024 = 16 waves.
// R25: hnth/hntl global stores moved AFTER the barrier, read from hbh/hbl
// LDS, ch-fastest -> fully coalesced (were 128B-stride 2B scatters).
// ---------------------------------------------------------------------------
__global__ __launch_bounds__(1024, 4) void k_convp(
  const int* __restrict__ flagp,
  const ushort* __restrict__ whah, const ushort* __restrict__ whal,
  const ushort* __restrict__ ht_hi, const ushort* __restrict__ ht_lo,
  const float* __restrict__ gxg, const ushort* __restrict__ gxo,
  const float* __restrict__ smalls, float* __restrict__ cst,
  const ushort* __restrict__ pwh, const ushort* __restrict__ pwl,
  const ushort* __restrict__ mth, const ushort* __restrict__ mtl,
  ushort* __restrict__ hnth, ushort* __restrict__ hntl,
  ushort* __restrict__ qb16, ushort* __restrict__ khb16, ushort* __restrict__ kmb16,
  ushort* __restrict__ vth16, ushort* __restrict__ vtm16, int t)
{
  __shared__ ushort albuf[16384];    // 16 waves x 1024 (in-place A refill)
  __shared__ ushort bsm[54*136];     // h halo hi+lo
  __shared__ ushort hbh[16*72];      // h-tile hi [px][cc], stride 72 (2-way)
  __shared__ ushort hbl[16*72];      // h-tile lo
  int nt = blockIdx.x, b = blockIdx.y;
  int tid = threadIdx.x;
  int flag = *flagp;
  int ytile = nt >> 1, x0 = (nt & 1) * 16;

  const ushort* hb  = ht_hi + (size_t)b*65536;
  const ushort* hlb = ht_lo + (size_t)b*65536;

  int w = tid >> 6, lane = tid & 63, lr = lane & 15, lk = lane >> 4;
  const ushort* aw  = whah + (size_t)(w*16)*64 + lane*8;   // + p*16384
  const ushort* awl = whal + (size_t)(w*16)*64 + lane*8;
  ushort* areg = albuf + w*1024;

  if (!flag){
    glds16(aw, areg);            // prefetch A(0), hides under halo staging
    glds16(aw + 512, areg + 512);
  }

  // acc init from precomputed X partials (loads issued early)
  int px = nt*16 + lr;
  int cc = w*4 + lk;
  int tb = b*8 + t;
  const ushort* go = gxo + ((size_t)tb*192 + cc*3)*1024 + px;
  float a0 = bu2f(go[0]);
  float a1 = bu2f(go[1024]);
  float a3 = bu2f(go[2048]);
  float a2 = gxg[((size_t)tb*64 + cc)*1024 + px];

  const uint4 Z16 = make_uint4(0,0,0,0);
  if (tid < 864){
    int slot = tid >> 4, c = tid & 15;
    int rr = slot / 18, xi = slot - rr*18;
    int gy = ytile - 1 + rr, gx2 = x0 - 1 + xi;
    bool valid = (gy >= 0) & (gy < 32) & (gx2 >= 0) & (gx2 < 32);
    int hpx = gy*32 + gx2;
    uint4 v = Z16;
    if (valid){
      if (c < 8) v = *reinterpret_cast<const uint4*>(hb  + (size_t)hpx*64 + c*8);
      else       v = *reinterpret_cast<const uint4*>(hlb + (size_t)hpx*64 + (c-8)*8);
    }
    *reinterpret_cast<uint4*>(&bsm[slot*136 + c*8]) = v;
  }
  __syncthreads();   // drains vmcnt+lgkmcnt -> A(0) resident, waits exact

  const int sw = lr & 7;
  const int c2n = ((lk ^ sw) << 3);
  const int c3n = (((4+lk) ^ sw) << 3);

  float4v acc = {a0, a1, a2, a3};

  if (!flag){
    #pragma unroll
    for (int p = 0; p < 9; ++p){
      if (p > 0){
        asm volatile("s_waitcnt vmcnt(0)" ::: "memory");
        __builtin_amdgcn_sched_barrier(0);
      }
      short8v A2 = ldfrag(areg + lr*64 + c2n);
      short8v A3 = ldfrag(areg + lr*64 + c3n);
      if (p < 8){
        asm volatile("s_waitcnt lgkmcnt(0)" ::: "memory");
        __builtin_amdgcn_sched_barrier(0);
        glds16(aw + (size_t)(p+1)*16384,       areg);
        glds16(aw + (size_t)(p+1)*16384 + 512, areg + 512);
        __builtin_amdgcn_sched_barrier(0);
      }
      int pinl = (p/3)*18 + lr + (p%3);
      const ushort* bl = &bsm[pinl*136 + lk*8];
      short8v BH0 = ldfrag(bl),    BH1 = ldfrag(bl+32);
      short8v BL0 = ldfrag(bl+64), BL1 = ldfrag(bl+96);
      acc = __builtin_amdgcn_mfma_f32_16x16x32_bf16(A2, BH0, acc, 0,0,0);
      acc = __builtin_amdgcn_mfma_f32_16x16x32_bf16(A3, BH1, acc, 0,0,0);
      acc = __builtin_amdgcn_mfma_f32_16x16x32_bf16(A2, BL0, acc, 0,0,0);
      acc = __builtin_amdgcn_mfma_f32_16x16x32_bf16(A3, BL1, acc, 0,0,0);
    }
  } else {
    // cold f32 path: in-place serial hi then lo per p
    #pragma unroll 1
    for (int p = 0; p < 9; ++p){
      glds16(aw + (size_t)p*16384,       areg);
      glds16(aw + (size_t)p*16384 + 512, areg + 512);
      asm volatile("s_waitcnt vmcnt(0)" ::: "memory");
      __builtin_amdgcn_sched_barrier(0);
      short8v A2 = ldfrag(areg + lr*64 + c2n);
      short8v A3 = ldfrag(areg + lr*64 + c3n);
      asm volatile("s_waitcnt lgkmcnt(0)" ::: "memory");
      __builtin_amdgcn_sched_barrier(0);
      glds16(awl + (size_t)p*16384,       areg);
      glds16(awl + (size_t)p*16384 + 512, areg + 512);
      asm volatile("s_waitcnt vmcnt(0)" ::: "memory");
      __builtin_amdgcn_sched_barrier(0);
      short8v Al2 = ldfrag(areg + lr*64 + c2n);
      short8v Al3 = ldfrag(areg + lr*64 + c3n);
      asm volatile("s_waitcnt lgkmcnt(0)" ::: "memory");
      __builtin_amdgcn_sched_barrier(0);
      int pinl = (p/3)*18 + lr + (p%3);
      const ushort* bl = &bsm[pinl*136 + lk*8];
      short8v BH0 = ldfrag(bl),    BH1 = ldfrag(bl+32);
      short8v BL0 = ldfrag(bl+64), BL1 = ldfrag(bl+96);
      acc = __builtin_amdgcn_mfma_f32_16x16x32_bf16(A2, BH0, acc, 0,0,0);
      acc = __builtin_amdgcn_mfma_f32_16x16x32_bf16(A3, BH1, acc, 0,0,0);
      acc = __builtin_amdgcn_mfma_f32_16x16x32_bf16(A2, BL0, acc, 0,0,0);
      acc = __builtin_amdgcn_mfma_f32_16x16x32_bf16(A3, BL1, acc, 0,0,0);
      acc = __builtin_amdgcn_mfma_f32_16x16x32_bf16(Al2, BH0, acc, 0,0,0);
      acc = __builtin_amdgcn_mfma_f32_16x16x32_bf16(Al3, BH1, acc, 0,0,0);
    }
  }

  // epilogue: peephole LSTM; h -> LDS hbh/hbl (global write after barrier)
  {
    int wi = cc*1024 + px;
    size_t sidx = ((size_t)(b*64 + cc))*1024 + px;
    float cprev = cst[sidx];
    float ic = acc[0] + smalls[O_CB + cc];
    float fc = acc[1] + smalls[O_CB + 64 + cc];
    float gc = acc[2] + smalls[O_CB + 128 + cc];
    float oc = acc[3] + smalls[O_CB + 192 + cc];
    float ig = sigm(ic + smalls[O_WCI + wi]*cprev);
    float fg = sigm(fc + smalls[O_WCF + wi]*cprev);
    float cnew = fg*cprev + ig*tanhc(gc);
    float og = sigm(oc + smalls[O_WCO + wi]*cnew);
    cst[sidx] = cnew;
    float hv = og*tanhc(cnew);
    ushort hh = f2bu(hv);
    ushort hl2 = f2bu(hv - bu2f(hh));
    hbh[lr*72 + cc] = hh;
    hbl[lr*72 + cc] = hl2;
  }
  __syncthreads();

  // coalesced hnT store: 1024 threads cover 16 px x 64 cc, cc fastest
  {
    int ppx = tid >> 6, ccx = tid & 63;
    size_t tix2 = ((size_t)b*1024 + nt*16 + ppx)*64 + ccx;
    hnth[tix2] = hbh[ppx*72 + ccx];
    hntl[tix2] = hbl[ppx*72 + ccx];
  }

  // ---------------- proj phase: waves 0..10, one tile each ----------------
  if (w < 11){
    int tt = w;
    const float4v Z4 = {0.f,0.f,0.f,0.f};
    bool srcm = (tt == 2) || (tt >= 7);
    short8v b0, b1, bl0, bl1;
    if (srcm){
      size_t bb = ((size_t)b*1024 + nt*16 + lr)*64 + lk*8;
      b0  = ldfrag(mth + bb);  b1  = ldfrag(mth + bb + 32);
      bl0 = ldfrag(mtl + bb);  bl1 = ldfrag(mtl + bb + 32);
    } else {
      b0  = ldfrag(&hbh[lr*72 + lk*8]);  b1  = ldfrag(&hbh[lr*72 + 32 + lk*8]);
      bl0 = ldfrag(&hbl[lr*72 + lk*8]);  bl1 = ldfrag(&hbl[lr*72 + 32 + lk*8]);
    }
    const ushort* ar = pwh + (size_t)(tt*16 + lr)*64 + lk*8;
    short8v pa0 = ldfrag(ar), pa1 = ldfrag(ar + 32);
    float4v d = Z4;
    d = __builtin_amdgcn_mfma_f32_16x16x32_bf16(pa0, b0,  d, 0,0,0);
    d = __builtin_amdgcn_mfma_f32_16x16x32_bf16(pa1, b1,  d, 0,0,0);
    d = __builtin_amdgcn_mfma_f32_16x16x32_bf16(pa0, bl0, d, 0,0,0);
    d = __builtin_amdgcn_mfma_f32_16x16x32_bf16(pa1, bl1, d, 0,0,0);
    if (flag){
      const ushort* arl = pwl + (size_t)(tt*16 + lr)*64 + lk*8;
      short8v pal0 = ldfrag(arl), pal1 = ldfrag(arl + 32);
      d = __builtin_amdgcn_mfma_f32_16x16x32_bf16(pal0, b0, d, 0,0,0);
      d = __builtin_amdgcn_mfma_f32_16x16x32_bf16(pal1, b1, d, 0,0,0);
    }
    int n = nt*16 + lr;
    int boff = (tt==0) ? O_QB : (tt==1) ? O_KB : (tt==2) ? O_K2B
             : (tt<7) ? (O_VB + (tt-3)*16) : (O_V2B + (tt-7)*16);
    if (tt < 3){
      ushort* base = (tt==0) ? qb16 : (tt==1) ? khb16 : kmb16;
      ushort u[4];
      #pragma unroll
      for (int q = 0; q < 4; ++q)
        u[q] = f2bu(d[q] + smalls[boff + lk*4 + q]);
      *reinterpret_cast<uint2*>(&base[((size_t)b*1024 + n)*32 + lk*4]) =
        make_uint2((unsigned)u[0] | ((unsigned)u[1]<<16),
                   (unsigned)u[2] | ((unsigned)u[3]<<16));
    } else {
      ushort* base = (tt<7) ? vth16 : vtm16;
      int cc0 = ((tt<7) ? (tt-3) : (tt-7))*16 + lk*4;
      #pragma unroll
      for (int q = 0; q < 4; ++q)
        base[((size_t)b*64 + cc0 + q)*1024 + n] = f2bu(d[q] + smalls[boff + lk*4 + q]);
    }
  }
}

// ---------------------------------------------------------------------------
// FUSED: MFMA flash attention (both branches) + MFMA zcomb GEMMs + gating.
// R23-proven double-buffered P-tile (one barrier per mc-chunk).
// R25: final T-array stores (hth/htl/mth/mtl) split into a ch-fastest loop
// -> fully coalesced 2B stores (were 128B-stride scatters). mst/out stay
// pp-fastest (already coalesced). Identical values, distinct addresses.
// ---------------------------------------------------------------------------
__global__ __launch_bounds__(512) void k_fattz(
  const ushort* __restrict__ qb16, const ushort* __restrict__ khb16,
  const ushort* __restrict__ kmb16, const ushort* __restrict__ vth16,
  const ushort* __restrict__ vtm16,
  const ushort* __restrict__ hnth, const ushort* __restrict__ hntl,
  const float* __restrict__ smalls,
  const ushort* __restrict__ zw16h, const ushort* __restrict__ zw16l,
  const ushort* __restrict__ mw16h, const ushort* __restrict__ mw16l,
  const int* __restrict__ flagp,
  float* __restrict__ mst, ushort* __restrict__ mth, ushort* __restrict__ mtl,
  ushort* __restrict__ hth, ushort* __restrict__ htl,
  void* __restrict__ outraw, int t)
{
  __shared__ __align__(16) unsigned char poolA[34816]; // es[2br][2buf] | zb | ho+mn
  __shared__ __align__(16) ushort ztbh[16*136];
  __shared__ __align__(16) ushort ztbl[16*136];
  __shared__ float cb[192*17];
  __shared__ float ml[64*17];
  __shared__ float rs_s[2][4][16];

  ushort* es   = (ushort*)poolA;              // [br][buf][16][272]
  ushort* zbh  = (ushort*)poolA;              // aliases es after attn
  ushort* zbl  = (ushort*)(poolA + 8704);
  float*  ho_s = (float*)poolA;
  float*  mn_s = (float*)(poolA + 4352);

  int nt = blockIdx.x, b = blockIdx.y;
  int n0 = nt*16;
  int tid = threadIdx.x;
  int w = tid >> 6, lane = tid & 63, lr = lane & 15, lk = lane >> 4;
  int br = w >> 2, wq = w & 3;
  int flag = *flagp;
  const float4v Z4 = {0.f,0.f,0.f,0.f};

  const ushort* kb = (br ? kmb16 : khb16) + (size_t)b*32768;
  const ushort* vt = (br ? vtm16 : vth16) + (size_t)b*65536;
  const ushort* qp = qb16 + (size_t)b*32768;

  for (int idx = tid; idx < 1024; idx += 512){
    int ch = idx >> 4, pp = idx & 15;
    ml[ch*17+pp] = mst[((size_t)b*64 + ch)*1024 + n0 + pp];
  }

  short8v qf = ldfrag(qp + (size_t)(n0 + lr)*32 + lk*8);

  float4v acc[2];
  acc[0]=Z4; acc[1]=Z4;
  float rsum = 0.f;

  #pragma unroll 1
  for (int mc = 0; mc < 4; ++mc){
    ushort* esb = es + (br*2 + (mc & 1))*4352;
    int mbase = mc*256 + wq*64;
    #pragma unroll
    for (int tau = 0; tau < 4; ++tau){
      short8v af = ldfrag(kb + (size_t)(mbase + tau*16 + lr)*32 + lk*8);
      float4v d = __builtin_amdgcn_mfma_f32_16x16x32_bf16(af, qf, Z4, 0,0,0);
      ushort u0 = f2bu(__expf(fminf(d[0], 60.f)));
      ushort u1 = f2bu(__expf(fminf(d[1], 60.f)));
      ushort u2 = f2bu(__expf(fminf(d[2], 60.f)));
      ushort u3 = f2bu(__expf(fminf(d[3], 60.f)));
      rsum += (bu2f(u0) + bu2f(u1)) + (bu2f(u2) + bu2f(u3));
      unsigned lo = (unsigned)u0 | ((unsigned)u1 << 16);
      unsigned hi = (unsigned)u2 | ((unsigned)u3 << 16);
      *reinterpret_cast<uint2*>(&esb[lr*272 + wq*64 + tau*16 + lk*4]) = make_uint2(lo, hi);
    }
    __syncthreads();
    #pragma unroll
    for (int ks = 0; ks < 8; ++ks){
      short8v av = ldfrag(vt + (size_t)(wq*16 + lr)*1024 + mc*256 + ks*32 + lk*8);
      short8v bv = ldfrag(&esb[lr*272 + ks*32 + lk*8]);
      acc[ks & 1] = __builtin_amdgcn_mfma_f32_16x16x32_bf16(av, bv, acc[ks & 1], 0,0,0);
    }
    // no trailing barrier: next mc writes the ALTERNATE buffer; the
    // mc+1 barrier orders those reads before mc+2's overwrite.
  }

  {
    float r = rsum;
    r += __shfl_xor(r, 16);
    r += __shfl_xor(r, 32);
    if (lane < 16) rs_s[br][wq][lr] = r;
  }
  __syncthreads();   // all PV reads done -> es region reusable as zb
  {
    float rinv = 1.0f / (rs_s[br][0][lr] + rs_s[br][1][lr] + rs_s[br][2][lr] + rs_s[br][3][lr]);
    int ch0 = br*64 + wq*16 + lk*4;
    ushort uh[4], ul[4];
    #pragma unroll
    for (int r = 0; r < 4; ++r){
      float z = (acc[0][r] + acc[1][r])*rinv;
      uh[r] = f2bu(z);
      ul[r] = f2bu(z - bu2f(uh[r]));
    }
    *reinterpret_cast<uint2*>(&zbh[lr*136 + ch0]) =
      make_uint2((unsigned)uh[0] | ((unsigned)uh[1]<<16), (unsigned)uh[2] | ((unsigned)uh[3]<<16));
    *reinterpret_cast<uint2*>(&zbl[lr*136 + ch0]) =
      make_uint2((unsigned)ul[0] | ((unsigned)ul[1]<<16), (unsigned)ul[2] | ((unsigned)ul[3]<<16));
  }
  __syncthreads();

  // ---------------- GEMM1: zt = z_w @ z + z_b ----------------
  {
    float4v zacc = Z4;
    if (!flag){
      #pragma unroll
      for (int kf = 0; kf < 4; ++kf){
        short8v a  = ldfrag(zw16h + (size_t)(w*16 + lr)*128 + kf*32 + lk*8);
        short8v bh = ldfrag(&zbh[lr*136 + kf*32 + lk*8]);
        short8v bl = ldfrag(&zbl[lr*136 + kf*32 + lk*8]);
        zacc = __builtin_amdgcn_mfma_f32_16x16x32_bf16(a, bh, zacc, 0,0,0);
        zacc = __builtin_amdgcn_mfma_f32_16x16x32_bf16(a, bl, zacc, 0,0,0);
      }
    } else {
      #pragma unroll
      for (int kf = 0; kf < 4; ++kf){
        short8v a  = ldfrag(zw16h + (size_t)(w*16 + lr)*128 + kf*32 + lk*8);
        short8v al = ldfrag(zw16l + (size_t)(w*16 + lr)*128 + kf*32 + lk*8);
        short8v bh = ldfrag(&zbh[lr*136 + kf*32 + lk*8]);
        short8v bl = ldfrag(&zbl[lr*136 + kf*32 + lk*8]);
        zacc = __builtin_amdgcn_mfma_f32_16x16x32_bf16(a,  bh, zacc, 0,0,0);
        zacc = __builtin_amdgcn_mfma_f32_16x16x32_bf16(a,  bl, zacc, 0,0,0);
        zacc = __builtin_amdgcn_mfma_f32_16x16x32_bf16(al, bh, zacc, 0,0,0);
      }
    }
    int r0 = w*16 + lk*4;
    ushort th[4], tl[4];
    #pragma unroll
    for (int q = 0; q < 4; ++q){
      float ztv = zacc[q] + smalls[O_ZB + r0 + q];
      th[q] = f2bu(ztv);
      tl[q] = f2bu(ztv - bu2f(th[q]));
    }
    *reinterpret_cast<uint2*>(&ztbh[lr*136 + r0]) =
      make_uint2((unsigned)th[0] | ((unsigned)th[1]<<16), (unsigned)th[2] | ((unsigned)th[3]<<16));
    *reinterpret_cast<uint2*>(&ztbl[lr*136 + r0]) =
      make_uint2((unsigned)tl[0] | ((unsigned)tl[1]<<16), (unsigned)tl[2] | ((unsigned)tl[3]<<16));
  }
  __syncthreads();

  // ------- GEMM2: comb = m_w @ [zt; h] + m_b -------
  const ushort* hrow  = hnth + ((size_t)b*1024 + n0 + lr)*64;
  const ushort* hrowl = hntl + ((size_t)b*1024 + n0 + lr)*64;
  #pragma unroll
  for (int mi = 0; mi < 2; ++mi){
    if (mi == 1 && w >= 4) break;
    int mf = (mi == 0) ? w : (w + 8);
    float4v cacc = Z4;
    const ushort* arow  = mw16h + (size_t)(mf*16 + lr)*192;
    const ushort* arowl = mw16l + (size_t)(mf*16 + lr)*192;
    if (!flag){
      #pragma unroll
      for (int kf = 0; kf < 4; ++kf){
        short8v a  = ldfrag(arow + kf*32 + lk*8);
        short8v bh = ldfrag(&ztbh[lr*136 + kf*32 + lk*8]);
        short8v bl = ldfrag(&ztbl[lr*136 + kf*32 + lk*8]);
        cacc = __builtin_amdgcn_mfma_f32_16x16x32_bf16(a, bh, cacc, 0,0,0);
        cacc = __builtin_amdgcn_mfma_f32_16x16x32_bf16(a, bl, cacc, 0,0,0);
      }
      #pragma unroll
      for (int kf = 0; kf < 2; ++kf){
        short8v a  = ldfrag(arow + 128 + kf*32 + lk*8);
        short8v bh = ldfrag(hrow + kf*32 + lk*8);
        short8v bl = ldfrag(hrowl + kf*32 + lk*8);
        cacc = __builtin_amdgcn_mfma_f32_16x16x32_bf16(a, bh, cacc, 0,0,0);
        cacc = __builtin_amdgcn_mfma_f32_16x16x32_bf16(a, bl, cacc, 0,0,0);
      }
    } else {
      #pragma unroll
      for (int kf = 0; kf < 4; ++kf){
        short8v a  = ldfrag(arow + kf*32 + lk*8);
        short8v al = ldfrag(arowl + kf*32 + lk*8);
        short8v bh = ldfrag(&ztbh[lr*136 + kf*32 + lk*8]);
        short8v bl = ldfrag(&ztbl[lr*136 + kf*32 + lk*8]);
        cacc = __builtin_amdgcn_mfma_f32_16x16x32_bf16(a,  bh, cacc, 0,0,0);
        cacc = __builtin_amdgcn_mfma_f32_16x16x32_bf16(a,  bl, cacc, 0,0,0);
        cacc = __builtin_amdgcn_mfma_f32_16x16x32_bf16(al, bh, cacc, 0,0,0);
      }
      #pragma unroll
      for (int kf = 0; kf < 2; ++kf){
        short8v a  = ldfrag(arow + 128 + kf*32 + lk*8);
        short8v al = ldfrag(arowl + 128 + kf*32 + lk*8);
        short8v bh = ldfrag(hrow + kf*32 + lk*8);
        short8v bl = ldfrag(hrowl + kf*32 + lk*8);
        cacc = __builtin_amdgcn_mfma_f32_16x16x32_bf16(a,  bh, cacc, 0,0,0);
        cacc = __builtin_amdgcn_mfma_f32_16x16x32_bf16(a,  bl, cacc, 0,0,0);
        cacc = __builtin_amdgcn_mfma_f32_16x16x32_bf16(al, bh, cacc, 0,0,0);
      }
    }
    int r0 = mf*16 + lk*4;
    #pragma unroll
    for (int q = 0; q < 4; ++q)
      cb[(r0+q)*17 + lr] = cacc[q] + smalls[O_MB + r0 + q];
  }
  __syncthreads();

  // ---------------- gating ----------------
  {
    int px = tid >> 5, lr2 = tid & 31;
    #pragma unroll
    for (int j = 0; j < 2; ++j){
      int ch = lr2 + 32*j;
      float mo = cb[ch*17 + px];
      float mg = cb[(64+ch)*17 + px];
      float mi = cb[(128+ch)*17 + px];
      float mold = ml[ch*17 + px];
      float gi = sigm(mi);
      float mnew = (1.0f-gi)*mold + gi*tanhc(mg);
      float ho = sigm(mo)*mnew;
      ho_s[ch*17+px] = ho;
      mn_s[ch*17+px] = mnew;
    }
  }
  __syncthreads();
  // loop 1 (pp-fastest): mst + out — both coalesced in n
  for (int idx = tid; idx < 1024; idx += 512){
    int ch = idx >> 4, pp = idx & 15;
    int n = n0 + pp;
    size_t gidx = ((size_t)b*64 + ch)*1024 + n;
    mst[gidx] = mn_s[ch*17+pp];
    float ho = ho_s[ch*17+pp];
    size_t oidx = ((size_t)(b*64+ch)*8 + t)*1024 + n;
    if (flag) ((float*)outraw)[oidx] = ho;
    else      ((bf16*)outraw)[oidx] = __float2bfloat16(ho);
  }
  // loop 2 (ch-fastest): T-layout arrays — coalesced 2B stores
  for (int idx = tid; idx < 1024; idx += 512){
    int pp = idx >> 6, ch = idx & 63;
    int n = n0 + pp;
    size_t tix = ((size_t)b*1024 + n)*64 + ch;
    float ho = ho_s[ch*17+pp];
    float mn = mn_s[ch*17+pp];
    ushort hb_ = f2bu(ho);
    hth[tix] = hb_;
    htl[tix] = f2bu(ho - bu2f(hb_));
    ushort mh_ = f2bu(mn);
    mth[tix] = mh_;
    mtl[tix] = f2bu(mn - bu2f(mh_));
  }
}

extern "C" void kernel_launch(void* const* d_in, const int* in_sizes, int n_in,
                              void* d_out, int out_size, void* d_ws, size_t ws_size,
                              hipStream_t stream)
{
  float* ws = (float*)d_ws;
  int* flag = (int*)(ws + WS_FLAG);
  float* c    = ws + WS_C;
  float* m    = ws + WS_M;
  float* gxg  = ws + WS_GXG;
  ushort* gxo   = (ushort*)(ws + WS_GXO);
  ushort* qb16  = (ushort*)(ws + WS_QB16);
  ushort* khb16 = (ushort*)(ws + WS_KHB16);
  ushort* kmb16 = (ushort*)(ws + WS_KMB16);
  ushort* vth16 = (ushort*)(ws + WS_VTH16);
  ushort* vtm16 = (ushort*)(ws + WS_VTM16);
  ushort* mth   = (ushort*)(ws + WS_MTH);
  ushort* mtl   = (ushort*)(ws + WS_MTL);
  ushort* hnth  = (ushort*)(ws + WS_HNTH);
  ushort* hntl  = (ushort*)(ws + WS_HNTL);
  ushort* zw16h = (ushort*)(ws + WS_ZW16H);
  ushort* zw16l = (ushort*)(ws + WS_ZW16L);
  ushort* mw16h = (ushort*)(ws + WS_MW16H);
  ushort* mw16l = (ushort*)(ws + WS_MW16L);
  ushort* wxah  = (ushort*)(ws + WS_WXAH);
  ushort* wxal  = (ushort*)(ws + WS_WXAL);
  ushort* whah  = (ushort*)(ws + WS_WHAH);
  ushort* whal  = (ushort*)(ws + WS_WHAL);
  ushort* xt_hi = (ushort*)(ws + WS_XTHI);
  ushort* xt_lo = (ushort*)(ws + WS_XTLO);
  ushort* ht_hi = (ushort*)(ws + WS_HTHI);
  ushort* ht_lo = (ushort*)(ws + WS_HTLO);
  ushort* pwh   = (ushort*)(ws + WS_PWH);
  ushort* pwl   = (ushort*)(ws + WS_PWL);

  k_probe<<<1, 256, 0, stream>>>((const unsigned int*)d_in[0], flag);
  P18 pk;
  for (int i = 0; i < 18; ++i) pk.p[i] = d_in[2 + i];
  k_wconv<<<dim3(64,18), 256, 0, stream>>>(pk, flag, ws);
  k_init<<<3072, 256, 0, stream>>>(d_in[1], flag, ws);
  k_xt<<<dim3(16,32), 256, 0, stream>>>(d_in[0], flag, ws);
  k_wtrans<<<144, 256, 0, stream>>>(ws);
  k_convx<<<dim3(64,2,32), 512, 0, stream>>>(flag, wxah, wxal, xt_hi, xt_lo, gxg, gxo);

  for (int t = 0; t < 8; ++t){
    k_convp<<<dim3(64,4), 1024, 0, stream>>>(flag, whah, whal, ht_hi, ht_lo,
                                             gxg, gxo, ws, c, pwh, pwl, mth, mtl,
                                             hnth, hntl, qb16, khb16, kmb16,
                                             vth16, vtm16, t);
    k_fattz<<<dim3(64,4), 512, 0, stream>>>(qb16, khb16, kmb16, vth16, vtm16,
                                            hnth, hntl, ws, zw16h, zw16l, mw16h, mw16l,
                                            flag, m, mth, mtl, ht_hi, ht_lo, d_out, t);
  }
  (void)in_sizes; (void)n_in; (void)out_size; (void)ws_size;
}

// Round 26
// 379.031 us; speedup vs baseline: 1.1116x; 1.0285x over previous
//
#include <hip/hip_runtime.h>
#include <hip/hip_bf16.h>

typedef __hip_bfloat16 bf16;
typedef unsigned short ushort;
typedef __attribute__((ext_vector_type(8))) short short8v;   // 8 bf16 = 4 VGPR
typedef __attribute__((ext_vector_type(4))) float float4v;

__device__ __forceinline__ float b2f(bf16 v){ return __bfloat162float(v); }
__device__ __forceinline__ float sigm(float x){ return 1.0f/(1.0f+__expf(-x)); }
__device__ __forceinline__ float tanhc(float x){
  x = fminf(15.0f, fmaxf(-15.0f, x));
  float e = __expf(2.0f*x);
  return (e-1.0f)/(e+1.0f);
}
__device__ __forceinline__ ushort f2bu(float f){
  bf16 h = __float2bfloat16(f); return *reinterpret_cast<ushort*>(&h);
}
__device__ __forceinline__ float bu2f(ushort u){
  return __uint_as_float(((unsigned)u)<<16);
}
__device__ __forceinline__ short8v ldfrag(const ushort* p){
  return *reinterpret_cast<const short8v*>(p);
}
// direct global->LDS DMA, 16B per lane; lds dst = uniform base + lane*16
__device__ __forceinline__ void glds16(const ushort* g, ushort* l){
  __builtin_amdgcn_global_load_lds(
    (const __attribute__((address_space(1))) unsigned int*)g,
    (__attribute__((address_space(3))) unsigned int*)l, 16, 0, 0);
}

// ---------------------------------------------------------------------------
// ws layout (float offsets)
// ---------------------------------------------------------------------------
#define WS_SMALL   0
#define WS_FLAG    262144
#define WS_ZROW    262160
#define WS_H       262208
#define WS_C       524352
#define WS_M       786496
#define WS_QB16    1310784
#define WS_KHB16   1376320
#define WS_KMB16   1441856
#define WS_VTH16   1507392
#define WS_VTM16   1638464
#define WS_MTH     1769536
#define WS_MTL     1900608
#define WS_HNTH    2031680
#define WS_HNTL    2162752
#define WS_ZW16H   2293824
#define WS_ZW16L   2302016
#define WS_MW16H   2310208
#define WS_MW16L   2328640
#define WS_WXAH    2347072     // 73728 f (147456 ushort) X weights hi
#define WS_WHAH    2420800     // 73728 f h weights hi
#define WS_WXAL    2494528     // 73728 f X weights lo
#define WS_WHAL    2568256     // 73728 f h weights lo
#define WS_XTHI    2641984
#define WS_XTLO    3690560
#define WS_HTHI    4739136
#define WS_HTLO    4870208
#define WS_PWH     5001280
#define WS_PWL     5006912
#define WS_GXG     5012544     // 2097152 f32: g-gate X-partial [bt][64cc][1024]
#define WS_GXO     7109696     // 6291456 ushort: i/f/o X-partials [bt][192][1024]
// total 10255424 f = 41.0 MB (ws known >= 45.2 MB from R2)
// small-weight offsets inside WS_SMALL
#define O_CB    0
#define O_WCI   256
#define O_WCF   65792
#define O_WCO   131328
#define O_QW    196864
#define O_QB    197888
#define O_KW    197904
#define O_KB    198928
#define O_K2W   198944
#define O_K2B   199968
#define O_VW    199984
#define O_VB    204080
#define O_V2W   204144
#define O_V2B   208240
#define O_ZW    208304
#define O_ZB    224688
#define O_MW    224816
#define O_MB    261680

// ---------------------------------------------------------------------------
// dtype probe (f32 vs bf16 input data)
// ---------------------------------------------------------------------------
__global__ void k_probe(const unsigned int* __restrict__ Xu, int* __restrict__ flag){
  __shared__ int cnt;
  if (threadIdx.x == 0) cnt = 0;
  __syncthreads();
  unsigned int u = Xu[threadIdx.x];
  float f = __uint_as_float((u & 0xffffu) << 16);
  int bad = (fabsf(f) <= 1e4f) ? 0 : 1;
  atomicAdd(&cnt, bad);
  __syncthreads();
  if (threadIdx.x == 0) *flag = (cnt > 16) ? 1 : 0;
}

// ---------------------------------------------------------------------------
// convert the 18 small inputs into f32 copies in ws
// ---------------------------------------------------------------------------
struct P18 { const void* p[18]; };

__global__ __launch_bounds__(256) void k_wconv(P18 pk, const int* __restrict__ flagp,
                                               float* __restrict__ dst){
  const int ns[18]   = {256,65536,65536,65536,1024,16,1024,16,1024,16,
                        4096,64,4096,64,16384,128,36864,192};
  const int offs[18] = {O_CB,O_WCI,O_WCF,O_WCO,O_QW,O_QB,O_KW,O_KB,O_K2W,O_K2B,
                        O_VW,O_VB,O_V2W,O_V2B,O_ZW,O_ZB,O_MW,O_MB};
  int y = blockIdx.y;
  int n = ns[y];
  int flag = *flagp;
  const void* src = pk.p[y];
  for (int i = blockIdx.x*256 + threadIdx.x; i < n; i += gridDim.x*256){
    float v = flag ? ((const float*)src)[i] : b2f(((const bf16*)src)[i]);
    dst[offs[y] + i] = v;
  }
}

// bf16 hi/lo copies: z_w (128x128), m_w (192x192), proj weights [176][64]
__global__ __launch_bounds__(256) void k_wtrans(float* __restrict__ ws){
  int i = blockIdx.x*256 + threadIdx.x;
  if (i < 16384){
    float f = ws[O_ZW + i];
    ushort h = f2bu(f);
    ((ushort*)(ws + WS_ZW16H))[i] = h;
    ((ushort*)(ws + WS_ZW16L))[i] = f2bu(f - bu2f(h));
  }
  if (i < 36864){
    float f = ws[O_MW + i];
    ushort h = f2bu(f);
    ((ushort*)(ws + WS_MW16H))[i] = h;
    ((ushort*)(ws + WS_MW16L))[i] = f2bu(f - bu2f(h));
  }
  if (i < 11264){
    int r = i >> 6, k = i & 63;
    float f;
    if (r < 16)       f = ws[O_QW  + r*64 + k];
    else if (r < 32)  f = ws[O_KW  + (r-16)*64 + k];
    else if (r < 48)  f = ws[O_K2W + (r-32)*64 + k];
    else if (r < 112) f = ws[O_VW  + (r-48)*64 + k];
    else              f = ws[O_V2W + (r-112)*64 + k];
    ushort h = f2bu(f);
    ((ushort*)(ws + WS_PWH))[i] = h;
    ((ushort*)(ws + WS_PWL))[i] = f2bu(f - bu2f(h));
  }
}

// ---------------------------------------------------------------------------
// init: zero states + hT + mT + q/k pad; split conv weights into X-only
// (wxa) and h-only (wha) layouts, both chunk-swizzled c ^= (mm&7) over
// 8 chunks of 8 ushort per 64-ci row.
// ---------------------------------------------------------------------------
__global__ __launch_bounds__(256) void k_init(const void* __restrict__ conv_w,
                                              const int* __restrict__ flagp,
                                              float* __restrict__ ws){
  int i = blockIdx.x*256 + threadIdx.x;
  int flag = *flagp;
  if (i < 786432) ws[WS_H + i] = 0.0f;
  if (i < 32) ws[WS_ZROW + i] = 0.0f;
  if (i < 196608) ((unsigned*)(ws + WS_QB16))[i] = 0u;   // qb/kh/km incl. pad
  if (i < 294912){
    int ci = i & 127;
    int j = i >> 7;           // j = p*256 + mm
    int mm = j & 255, p = j >> 8;
    int cc = mm >> 2, g = mm & 3;
    int si = ((g*64 + cc)*128 + ci)*9 + p;
    float f;
    ushort hi, lo = 0;
    if (flag){
      f = ((const float*)conv_w)[si];
      hi = f2bu(f);
      lo = f2bu(f - bu2f(hi));
    } else {
      hi = ((const ushort*)conv_w)[si];
    }
    if (ci < 64){
      int di = (j << 6) + ((((ci >> 3) ^ (mm & 7)) << 3) | (ci & 7));
      ((ushort*)(ws + WS_WXAH))[di] = hi;
      ((ushort*)(ws + WS_WXAL))[di] = lo;
    } else {
      int c2 = ci - 64;
      int di = (j << 6) + ((((c2 >> 3) ^ (mm & 7)) << 3) | (c2 & 7));
      ((ushort*)(ws + WS_WHAH))[di] = hi;
      ((ushort*)(ws + WS_WHAL))[di] = lo;
    }
  }
  if (i < 131072){
    ((unsigned*)(ws + WS_HTHI))[i] = 0u;
    ((unsigned*)(ws + WS_HTLO))[i] = 0u;
    ((unsigned*)(ws + WS_MTH))[i] = 0u;
    ((unsigned*)(ws + WS_MTL))[i] = 0u;
  }
}

// ---------------------------------------------------------------------------
// X transpose: XT[b][t][px][ci]
// ---------------------------------------------------------------------------
__global__ __launch_bounds__(256) void k_xt(const void* __restrict__ Xraw,
                                            const int* __restrict__ flagp,
                                            float* __restrict__ ws){
  __shared__ ushort hi_s[64][66];
  __shared__ ushort lo_s[64][66];
  int pt = blockIdx.x, s = blockIdx.y;
  int b = s >> 3, t = s & 7;
  int flag = *flagp;
  int tid = threadIdx.x;
  for (int k = 0; k < 16; ++k){
    int idx = tid + k*256;
    int ci = idx >> 6, pxl = idx & 63;
    size_t si = ((size_t)(b*64 + ci)*8 + t)*1024 + pt*64 + pxl;
    if (flag){
      float f = ((const float*)Xraw)[si];
      ushort h = f2bu(f);
      hi_s[pxl][ci] = h;
      lo_s[pxl][ci] = f2bu(f - bu2f(h));
    } else {
      hi_s[pxl][ci] = ((const ushort*)Xraw)[si];
    }
  }
  __syncthreads();
  ushort* xh = (ushort*)(ws + WS_XTHI) + ((size_t)s*1024 + pt*64)*64;
  ushort* xl = (ushort*)(ws + WS_XTLO) + ((size_t)s*1024 + pt*64)*64;
  for (int k = 0; k < 16; ++k){
    int idx = tid + k*256;
    int pxl = idx >> 6, ci = idx & 63;
    xh[pxl*64 + ci] = hi_s[pxl][ci];
    if (flag) xl[pxl*64 + ci] = lo_s[pxl][ci];
  }
}

// ---------------------------------------------------------------------------
// k_convx: time-invariant X-part of the conv gates for ALL (b,t) at once.
// grid (64 nt, 2 mh, 32 bt) = 4096 blocks, block 512 = 8 waves.
// R18/R23-proven structure. CLOSED: R19 counted-vmcnt, R20 4x-reuse, and
// R24 occupancy-neutral dbuf all regressed (R24: L2 write-combining broke,
// WRITE_SIZE 20->53 MB). Do not touch.
// ---------------------------------------------------------------------------
__global__ __launch_bounds__(512, 4) void k_convx(
  const int* __restrict__ flagp,
  const ushort* __restrict__ wxah, const ushort* __restrict__ wxal,
  const ushort* __restrict__ xt_hi, const ushort* __restrict__ xt_lo,
  float* __restrict__ gxg, ushort* __restrict__ gxo)
{
  __shared__ ushort xabuf[8192];     // 8 waves x 1024 ushort (A slices)
  __shared__ ushort xsm[54*136];     // X halo (hi + optional lo)
  int nt = blockIdx.x, mh = blockIdx.y, tb = blockIdx.z;
  int tid = threadIdx.x;
  int flag = *flagp;
  int ytile = nt >> 1, x0 = (nt & 1) * 16;
  const ushort* xb  = xt_hi + (size_t)tb*65536;
  const ushort* xlb = xt_lo + (size_t)tb*65536;
  int w = tid >> 6, lane = tid & 63, lr = lane & 15, lk = lane >> 4;
  const ushort* aw  = wxah + (size_t)(mh*128 + w*16)*64 + lane*8;  // + p*16384
  const ushort* awl = wxal + (size_t)(mh*128 + w*16)*64 + lane*8;
  ushort* areg = xabuf + w*1024;

  const uint4 Z16 = make_uint4(0,0,0,0);
  for (int idx = tid; idx < 864; idx += 512){
    int slot = idx >> 4, c = idx & 15;
    int rr = slot / 18, xi = slot - rr*18;
    int gy = ytile - 1 + rr, gx2 = x0 - 1 + xi;
    bool valid = (gy >= 0) & (gy < 32) & (gx2 >= 0) & (gx2 < 32);
    int px = gy*32 + gx2;
    uint4 v = Z16;
    if (valid){
      if (c < 8)       v = *reinterpret_cast<const uint4*>(xb  + (size_t)px*64 + c*8);
      else if (flag)   v = *reinterpret_cast<const uint4*>(xlb + (size_t)px*64 + (c-8)*8);
    }
    *reinterpret_cast<uint4*>(&xsm[slot*136 + c*8]) = v;
  }
  __syncthreads();

  int px = nt*16 + lr;
  int sw = lr & 7;
  const int cx0 = ((lk ^ sw) << 3);
  const int cx1 = (((4+lk) ^ sw) << 3);
  float4v acc = {0.f,0.f,0.f,0.f};

  #pragma unroll 1
  for (int p = 0; p < 9; ++p){
    glds16(aw + (size_t)p*16384,       areg);
    glds16(aw + (size_t)p*16384 + 512, areg + 512);
    asm volatile("s_waitcnt vmcnt(0)" ::: "memory");
    __builtin_amdgcn_sched_barrier(0);
    short8v A0 = ldfrag(areg + lr*64 + cx0);
    short8v A1 = ldfrag(areg + lr*64 + cx1);
    int pinl = (p/3)*18 + lr + (p%3);
    const ushort* bl = &xsm[pinl*136 + lk*8];
    short8v BX0 = ldfrag(bl), BX1 = ldfrag(bl+32);
    acc = __builtin_amdgcn_mfma_f32_16x16x32_bf16(A0, BX0, acc, 0,0,0);
    acc = __builtin_amdgcn_mfma_f32_16x16x32_bf16(A1, BX1, acc, 0,0,0);
    if (flag){
      short8v BXl0 = ldfrag(bl+64), BXl1 = ldfrag(bl+96);
      acc = __builtin_amdgcn_mfma_f32_16x16x32_bf16(A0, BXl0, acc, 0,0,0);
      acc = __builtin_amdgcn_mfma_f32_16x16x32_bf16(A1, BXl1, acc, 0,0,0);
      asm volatile("s_waitcnt lgkmcnt(0)" ::: "memory");
      __builtin_amdgcn_sched_barrier(0);
      glds16(awl + (size_t)p*16384,       areg);
      glds16(awl + (size_t)p*16384 + 512, areg + 512);
      asm volatile("s_waitcnt vmcnt(0)" ::: "memory");
      __builtin_amdgcn_sched_barrier(0);
      short8v Al0 = ldfrag(areg + lr*64 + cx0);
      short8v Al1 = ldfrag(areg + lr*64 + cx1);
      acc = __builtin_amdgcn_mfma_f32_16x16x32_bf16(Al0, BX0, acc, 0,0,0);
      acc = __builtin_amdgcn_mfma_f32_16x16x32_bf16(Al1, BX1, acc, 0,0,0);
      asm volatile("s_waitcnt lgkmcnt(0)" ::: "memory");
      __builtin_amdgcn_sched_barrier(0);
    } else {
      asm volatile("s_waitcnt lgkmcnt(0)" ::: "memory");   // areg reusable
      __builtin_amdgcn_sched_barrier(0);
    }
  }

  {
    int cc = mh*32 + w*4 + lk;
    gxg[((size_t)tb*64 + cc)*1024 + px] = acc[2];
    ushort* go = gxo + ((size_t)tb*192 + cc*3)*1024 + px;
    go[0]    = f2bu(acc[0]);
    go[1024] = f2bu(acc[1]);
    go[2048] = f2bu(acc[3]);
  }
}

// ---------------------------------------------------------------------------
// FUSED conv (h-part) + peephole LSTM + 1x1 projections (R25-proven).
// grid (64 nt, 4 b) = 256 blocks, block 1024 = 16 waves.
// ---------------------------------------------------------------------------
__global__ __launch_bounds__(1024, 4) void k_convp(
  const int* __restrict__ flagp,
  const ushort* __restrict__ whah, const ushort* __restrict__ whal,
  const ushort* __restrict__ ht_hi, const ushort* __restrict__ ht_lo,
  const float* __restrict__ gxg, const ushort* __restrict__ gxo,
  const float* __restrict__ smalls, float* __restrict__ cst,
  const ushort* __restrict__ pwh, const ushort* __restrict__ pwl,
  const ushort* __restrict__ mth, const ushort* __restrict__ mtl,
  ushort* __restrict__ hnth, ushort* __restrict__ hntl,
  ushort* __restrict__ qb16, ushort* __restrict__ khb16, ushort* __restrict__ kmb16,
  ushort* __restrict__ vth16, ushort* __restrict__ vtm16, int t)
{
  __shared__ ushort albuf[16384];    // 16 waves x 1024 (in-place A refill)
  __shared__ ushort bsm[54*136];     // h halo hi+lo
  __shared__ ushort hbh[16*72];      // h-tile hi [px][cc], stride 72 (2-way)
  __shared__ ushort hbl[16*72];      // h-tile lo
  int nt = blockIdx.x, b = blockIdx.y;
  int tid = threadIdx.x;
  int flag = *flagp;
  int ytile = nt >> 1, x0 = (nt & 1) * 16;

  const ushort* hb  = ht_hi + (size_t)b*65536;
  const ushort* hlb = ht_lo + (size_t)b*65536;

  int w = tid >> 6, lane = tid & 63, lr = lane & 15, lk = lane >> 4;
  const ushort* aw  = whah + (size_t)(w*16)*64 + lane*8;   // + p*16384
  const ushort* awl = whal + (size_t)(w*16)*64 + lane*8;
  ushort* areg = albuf + w*1024;

  if (!flag){
    glds16(aw, areg);            // prefetch A(0), hides under halo staging
    glds16(aw + 512, areg + 512);
  }

  // acc init from precomputed X partials (loads issued early)
  int px = nt*16 + lr;
  int cc = w*4 + lk;
  int tb = b*8 + t;
  const ushort* go = gxo + ((size_t)tb*192 + cc*3)*1024 + px;
  float a0 = bu2f(go[0]);
  float a1 = bu2f(go[1024]);
  float a3 = bu2f(go[2048]);
  float a2 = gxg[((size_t)tb*64 + cc)*1024 + px];

  const uint4 Z16 = make_uint4(0,0,0,0);
  if (tid < 864){
    int slot = tid >> 4, c = tid & 15;
    int rr = slot / 18, xi = slot - rr*18;
    int gy = ytile - 1 + rr, gx2 = x0 - 1 + xi;
    bool valid = (gy >= 0) & (gy < 32) & (gx2 >= 0) & (gx2 < 32);
    int hpx = gy*32 + gx2;
    uint4 v = Z16;
    if (valid){
      if (c < 8) v = *reinterpret_cast<const uint4*>(hb  + (size_t)hpx*64 + c*8);
      else       v = *reinterpret_cast<const uint4*>(hlb + (size_t)hpx*64 + (c-8)*8);
    }
    *reinterpret_cast<uint4*>(&bsm[slot*136 + c*8]) = v;
  }
  __syncthreads();   // drains vmcnt+lgkmcnt -> A(0) resident, waits exact

  const int sw = lr & 7;
  const int c2n = ((lk ^ sw) << 3);
  const int c3n = (((4+lk) ^ sw) << 3);

  float4v acc = {a0, a1, a2, a3};

  if (!flag){
    #pragma unroll
    for (int p = 0; p < 9; ++p){
      if (p > 0){
        asm volatile("s_waitcnt vmcnt(0)" ::: "memory");
        __builtin_amdgcn_sched_barrier(0);
      }
      short8v A2 = ldfrag(areg + lr*64 + c2n);
      short8v A3 = ldfrag(areg + lr*64 + c3n);
      if (p < 8){
        asm volatile("s_waitcnt lgkmcnt(0)" ::: "memory");
        __builtin_amdgcn_sched_barrier(0);
        glds16(aw + (size_t)(p+1)*16384,       areg);
        glds16(aw + (size_t)(p+1)*16384 + 512, areg + 512);
        __builtin_amdgcn_sched_barrier(0);
      }
      int pinl = (p/3)*18 + lr + (p%3);
      const ushort* bl = &bsm[pinl*136 + lk*8];
      short8v BH0 = ldfrag(bl),    BH1 = ldfrag(bl+32);
      short8v BL0 = ldfrag(bl+64), BL1 = ldfrag(bl+96);
      acc = __builtin_amdgcn_mfma_f32_16x16x32_bf16(A2, BH0, acc, 0,0,0);
      acc = __builtin_amdgcn_mfma_f32_16x16x32_bf16(A3, BH1, acc, 0,0,0);
      acc = __builtin_amdgcn_mfma_f32_16x16x32_bf16(A2, BL0, acc, 0,0,0);
      acc = __builtin_amdgcn_mfma_f32_16x16x32_bf16(A3, BL1, acc, 0,0,0);
    }
  } else {
    // cold f32 path: in-place serial hi then lo per p
    #pragma unroll 1
    for (int p = 0; p < 9; ++p){
      glds16(aw + (size_t)p*16384,       areg);
      glds16(aw + (size_t)p*16384 + 512, areg + 512);
      asm volatile("s_waitcnt vmcnt(0)" ::: "memory");
      __builtin_amdgcn_sched_barrier(0);
      short8v A2 = ldfrag(areg + lr*64 + c2n);
      short8v A3 = ldfrag(areg + lr*64 + c3n);
      asm volatile("s_waitcnt lgkmcnt(0)" ::: "memory");
      __builtin_amdgcn_sched_barrier(0);
      glds16(awl + (size_t)p*16384,       areg);
      glds16(awl + (size_t)p*16384 + 512, areg + 512);
      asm volatile("s_waitcnt vmcnt(0)" ::: "memory");
      __builtin_amdgcn_sched_barrier(0);
      short8v Al2 = ldfrag(areg + lr*64 + c2n);
      short8v Al3 = ldfrag(areg + lr*64 + c3n);
      asm volatile("s_waitcnt lgkmcnt(0)" ::: "memory");
      __builtin_amdgcn_sched_barrier(0);
      int pinl = (p/3)*18 + lr + (p%3);
      const ushort* bl = &bsm[pinl*136 + lk*8];
      short8v BH0 = ldfrag(bl),    BH1 = ldfrag(bl+32);
      short8v BL0 = ldfrag(bl+64), BL1 = ldfrag(bl+96);
      acc = __builtin_amdgcn_mfma_f32_16x16x32_bf16(A2, BH0, acc, 0,0,0);
      acc = __builtin_amdgcn_mfma_f32_16x16x32_bf16(A3, BH1, acc, 0,0,0);
      acc = __builtin_amdgcn_mfma_f32_16x16x32_bf16(A2, BL0, acc, 0,0,0);
      acc = __builtin_amdgcn_mfma_f32_16x16x32_bf16(A3, BL1, acc, 0,0,0);
      acc = __builtin_amdgcn_mfma_f32_16x16x32_bf16(Al2, BH0, acc, 0,0,0);
      acc = __builtin_amdgcn_mfma_f32_16x16x32_bf16(Al3, BH1, acc, 0,0,0);
    }
  }

  // epilogue: peephole LSTM; h -> LDS hbh/hbl (global write after barrier)
  {
    int wi = cc*1024 + px;
    size_t sidx = ((size_t)(b*64 + cc))*1024 + px;
    float cprev = cst[sidx];
    float ic = acc[0] + smalls[O_CB + cc];
    float fc = acc[1] + smalls[O_CB + 64 + cc];
    float gc = acc[2] + smalls[O_CB + 128 + cc];
    float oc = acc[3] + smalls[O_CB + 192 + cc];
    float ig = sigm(ic + smalls[O_WCI + wi]*cprev);
    float fg = sigm(fc + smalls[O_WCF + wi]*cprev);
    float cnew = fg*cprev + ig*tanhc(gc);
    float og = sigm(oc + smalls[O_WCO + wi]*cnew);
    cst[sidx] = cnew;
    float hv = og*tanhc(cnew);
    ushort hh = f2bu(hv);
    ushort hl2 = f2bu(hv - bu2f(hh));
    hbh[lr*72 + cc] = hh;
    hbl[lr*72 + cc] = hl2;
  }
  __syncthreads();

  // coalesced hnT store: 1024 threads cover 16 px x 64 cc, cc fastest
  {
    int ppx = tid >> 6, ccx = tid & 63;
    size_t tix2 = ((size_t)b*1024 + nt*16 + ppx)*64 + ccx;
    hnth[tix2] = hbh[ppx*72 + ccx];
    hntl[tix2] = hbl[ppx*72 + ccx];
  }

  // ---------------- proj phase: waves 0..10, one tile each ----------------
  if (w < 11){
    int tt = w;
    const float4v Z4 = {0.f,0.f,0.f,0.f};
    bool srcm = (tt == 2) || (tt >= 7);
    short8v b0, b1, bl0, bl1;
    if (srcm){
      size_t bb = ((size_t)b*1024 + nt*16 + lr)*64 + lk*8;
      b0  = ldfrag(mth + bb);  b1  = ldfrag(mth + bb + 32);
      bl0 = ldfrag(mtl + bb);  bl1 = ldfrag(mtl + bb + 32);
    } else {
      b0  = ldfrag(&hbh[lr*72 + lk*8]);  b1  = ldfrag(&hbh[lr*72 + 32 + lk*8]);
      bl0 = ldfrag(&hbl[lr*72 + lk*8]);  bl1 = ldfrag(&hbl[lr*72 + 32 + lk*8]);
    }
    const ushort* ar = pwh + (size_t)(tt*16 + lr)*64 + lk*8;
    short8v pa0 = ldfrag(ar), pa1 = ldfrag(ar + 32);
    float4v d = Z4;
    d = __builtin_amdgcn_mfma_f32_16x16x32_bf16(pa0, b0,  d, 0,0,0);
    d = __builtin_amdgcn_mfma_f32_16x16x32_bf16(pa1, b1,  d, 0,0,0);
    d = __builtin_amdgcn_mfma_f32_16x16x32_bf16(pa0, bl0, d, 0,0,0);
    d = __builtin_amdgcn_mfma_f32_16x16x32_bf16(pa1, bl1, d, 0,0,0);
    if (flag){
      const ushort* arl = pwl + (size_t)(tt*16 + lr)*64 + lk*8;
      short8v pal0 = ldfrag(arl), pal1 = ldfrag(arl + 32);
      d = __builtin_amdgcn_mfma_f32_16x16x32_bf16(pal0, b0, d, 0,0,0);
      d = __builtin_amdgcn_mfma_f32_16x16x32_bf16(pal1, b1, d, 0,0,0);
    }
    int n = nt*16 + lr;
    int boff = (tt==0) ? O_QB : (tt==1) ? O_KB : (tt==2) ? O_K2B
             : (tt<7) ? (O_VB + (tt-3)*16) : (O_V2B + (tt-7)*16);
    if (tt < 3){
      ushort* base = (tt==0) ? qb16 : (tt==1) ? khb16 : kmb16;
      ushort u[4];
      #pragma unroll
      for (int q = 0; q < 4; ++q)
        u[q] = f2bu(d[q] + smalls[boff + lk*4 + q]);
      *reinterpret_cast<uint2*>(&base[((size_t)b*1024 + n)*32 + lk*4]) =
        make_uint2((unsigned)u[0] | ((unsigned)u[1]<<16),
                   (unsigned)u[2] | ((unsigned)u[3]<<16));
    } else {
      ushort* base = (tt<7) ? vth16 : vtm16;
      int cc0 = ((tt<7) ? (tt-3) : (tt-7))*16 + lk*4;
      #pragma unroll
      for (int q = 0; q < 4; ++q)
        base[((size_t)b*64 + cc0 + q)*1024 + n] = f2bu(d[q] + smalls[boff + lk*4 + q]);
    }
  }
}

// ---------------------------------------------------------------------------
// FUSED: MFMA flash attention (both branches) + MFMA zcomb GEMMs + gating.
// R26 change: 1024 threads / 16 waves (was 512/8 -> only 2 waves/SIMD).
// Each branch's m-scan splits across 2 warp-groups (mh2), each covering
// 2 of the 4 mc-chunks into its OWN dedicated es buffer (8 buffers, no
// reuse -> 2 barriers in the attention loop). Partial PV accs combined
// via dedicated accx LDS (f32 reassociation only). GEMM1 on warps 0..7
// (unchanged math), GEMM2 flattened onto warps 0..11, gating/stores
// single-pass. LDS ~102.5 KB; grid 256 = 1 block/CU regardless.
// ---------------------------------------------------------------------------
__global__ __launch_bounds__(1024) void k_fattz(
  const ushort* __restrict__ qb16, const ushort* __restrict__ khb16,
  const ushort* __restrict__ kmb16, const ushort* __restrict__ vth16,
  const ushort* __restrict__ vtm16,
  const ushort* __restrict__ hnth, const ushort* __restrict__ hntl,
  const float* __restrict__ smalls,
  const ushort* __restrict__ zw16h, const ushort* __restrict__ zw16l,
  const ushort* __restrict__ mw16h, const ushort* __restrict__ mw16l,
  const int* __restrict__ flagp,
  float* __restrict__ mst, ushort* __restrict__ mth, ushort* __restrict__ mtl,
  ushort* __restrict__ hth, ushort* __restrict__ htl,
  void* __restrict__ outraw, int t)
{
  __shared__ __align__(16) unsigned char poolA[69632]; // es[2br][4mc] | zb | ho+mn
  __shared__ __align__(16) ushort ztbh[16*136];
  __shared__ __align__(16) ushort ztbl[16*136];
  __shared__ float cb[192*17];
  __shared__ float ml[64*17];
  __shared__ float rs_s[2][8][16];
  __shared__ float accx[2*4*64*4];   // (br,wq,lane) float4: mh2=1 partial accs

  ushort* es   = (ushort*)poolA;              // 8 buffers x [16][272]
  ushort* zbh  = (ushort*)poolA;              // aliases es after attn
  ushort* zbl  = (ushort*)(poolA + 8704);
  float*  ho_s = (float*)poolA;
  float*  mn_s = (float*)(poolA + 4352);

  int nt = blockIdx.x, b = blockIdx.y;
  int n0 = nt*16;
  int tid = threadIdx.x;
  int w = tid >> 6, lane = tid & 63, lr = lane & 15, lk = lane >> 4;
  int br = w >> 3, sub = w & 7, mh2 = sub >> 2, wq = sub & 3;
  int flag = *flagp;
  const float4v Z4 = {0.f,0.f,0.f,0.f};

  const ushort* kb = (br ? kmb16 : khb16) + (size_t)b*32768;
  const ushort* vt = (br ? vtm16 : vth16) + (size_t)b*65536;
  const ushort* qp = qb16 + (size_t)b*32768;

  {
    int ch = tid >> 4, pp = tid & 15;
    ml[ch*17+pp] = mst[((size_t)b*64 + ch)*1024 + n0 + pp];
  }

  short8v qf = ldfrag(qp + (size_t)(n0 + lr)*32 + lk*8);

  float4v acc[2];
  acc[0]=Z4; acc[1]=Z4;
  float rsum = 0.f;

  #pragma unroll 1
  for (int mci = 0; mci < 2; ++mci){
    int mc = mh2*2 + mci;
    ushort* esb = es + (size_t)(br*4 + mc)*4352;
    int mbase = mc*256 + wq*64;
    #pragma unroll
    for (int tau = 0; tau < 4; ++tau){
      short8v af = ldfrag(kb + (size_t)(mbase + tau*16 + lr)*32 + lk*8);
      float4v d = __builtin_amdgcn_mfma_f32_16x16x32_bf16(af, qf, Z4, 0,0,0);
      ushort u0 = f2bu(__expf(fminf(d[0], 60.f)));
      ushort u1 = f2bu(__expf(fminf(d[1], 60.f)));
      ushort u2 = f2bu(__expf(fminf(d[2], 60.f)));
      ushort u3 = f2bu(__expf(fminf(d[3], 60.f)));
      rsum += (bu2f(u0) + bu2f(u1)) + (bu2f(u2) + bu2f(u3));
      unsigned lo = (unsigned)u0 | ((unsigned)u1 << 16);
      unsigned hi = (unsigned)u2 | ((unsigned)u3 << 16);
      *reinterpret_cast<uint2*>(&esb[lr*272 + wq*64 + tau*16 + lk*4]) = make_uint2(lo, hi);
    }
    __syncthreads();
    #pragma unroll
    for (int ks = 0; ks < 8; ++ks){
      short8v av = ldfrag(vt + (size_t)(wq*16 + lr)*1024 + mc*256 + ks*32 + lk*8);
      short8v bv = ldfrag(&esb[lr*272 + ks*32 + lk*8]);
      acc[ks & 1] = __builtin_amdgcn_mfma_f32_16x16x32_bf16(av, bv, acc[ks & 1], 0,0,0);
    }
    // no trailing barrier: each (br,mc) has its own buffer, never reused.
  }

  {
    float r = rsum;
    r += __shfl_xor(r, 16);
    r += __shfl_xor(r, 32);
    if (lane < 16) rs_s[br][sub][lr] = r;
  }
  if (mh2 == 1){
    float* ax = accx + ((size_t)(br*4 + wq)*64 + lane)*4;
    #pragma unroll
    for (int r = 0; r < 4; ++r) ax[r] = acc[0][r] + acc[1][r];
  }
  __syncthreads();   // rs_s/accx visible; all PV reads done -> es reusable as zb
  if (mh2 == 0){
    float rtot = 0.f;
    #pragma unroll
    for (int s2 = 0; s2 < 8; ++s2) rtot += rs_s[br][s2][lr];
    float rinv = 1.0f / rtot;
    const float* ax = accx + ((size_t)(br*4 + wq)*64 + lane)*4;
    int ch0 = br*64 + wq*16 + lk*4;
    ushort uh[4], ul[4];
    #pragma unroll
    for (int r = 0; r < 4; ++r){
      float z = (acc[0][r] + acc[1][r] + ax[r])*rinv;
      uh[r] = f2bu(z);
      ul[r] = f2bu(z - bu2f(uh[r]));
    }
    *reinterpret_cast<uint2*>(&zbh[lr*136 + ch0]) =
      make_uint2((unsigned)uh[0] | ((unsigned)uh[1]<<16), (unsigned)uh[2] | ((unsigned)uh[3]<<16));
    *reinterpret_cast<uint2*>(&zbl[lr*136 + ch0]) =
      make_uint2((unsigned)ul[0] | ((unsigned)ul[1]<<16), (unsigned)ul[2] | ((unsigned)ul[3]<<16));
  }
  __syncthreads();

  // ---------------- GEMM1: zt = z_w @ z + z_b (warps 0..7) ----------------
  if (w < 8){
    float4v zacc = Z4;
    if (!flag){
      #pragma unroll
      for (int kf = 0; kf < 4; ++kf){
        short8v a  = ldfrag(zw16h + (size_t)(w*16 + lr)*128 + kf*32 + lk*8);
        short8v bh = ldfrag(&zbh[lr*136 + kf*32 + lk*8]);
        short8v bl = ldfrag(&zbl[lr*136 + kf*32 + lk*8]);
        zacc = __builtin_amdgcn_mfma_f32_16x16x32_bf16(a, bh, zacc, 0,0,0);
        zacc = __builtin_amdgcn_mfma_f32_16x16x32_bf16(a, bl, zacc, 0,0,0);
      }
    } else {
      #pragma unroll
      for (int kf = 0; kf < 4; ++kf){
        short8v a  = ldfrag(zw16h + (size_t)(w*16 + lr)*128 + kf*32 + lk*8);
        short8v al = ldfrag(zw16l + (size_t)(w*16 + lr)*128 + kf*32 + lk*8);
        short8v bh = ldfrag(&zbh[lr*136 + kf*32 + lk*8]);
        short8v bl = ldfrag(&zbl[lr*136 + kf*32 + lk*8]);
        zacc = __builtin_amdgcn_mfma_f32_16x16x32_bf16(a,  bh, zacc, 0,0,0);
        zacc = __builtin_amdgcn_mfma_f32_16x16x32_bf16(a,  bl, zacc, 0,0,0);
        zacc = __builtin_amdgcn_mfma_f32_16x16x32_bf16(al, bh, zacc, 0,0,0);
      }
    }
    int r0 = w*16 + lk*4;
    ushort th[4], tl[4];
    #pragma unroll
    for (int q = 0; q < 4; ++q){
      float ztv = zacc[q] + smalls[O_ZB + r0 + q];
      th[q] = f2bu(ztv);
      tl[q] = f2bu(ztv - bu2f(th[q]));
    }
    *reinterpret_cast<uint2*>(&ztbh[lr*136 + r0]) =
      make_uint2((unsigned)th[0] | ((unsigned)th[1]<<16), (unsigned)th[2] | ((unsigned)th[3]<<16));
    *reinterpret_cast<uint2*>(&ztbl[lr*136 + r0]) =
      make_uint2((unsigned)tl[0] | ((unsigned)tl[1]<<16), (unsigned)tl[2] | ((unsigned)tl[3]<<16));
  }
  __syncthreads();

  // ------- GEMM2: comb = m_w @ [zt; h] + m_b (warps 0..11, one tile each) -------
  const ushort* hrow  = hnth + ((size_t)b*1024 + n0 + lr)*64;
  const ushort* hrowl = hntl + ((size_t)b*1024 + n0 + lr)*64;
  if (w < 12){
    int mf = w;
    float4v cacc = Z4;
    const ushort* arow  = mw16h + (size_t)(mf*16 + lr)*192;
    const ushort* arowl = mw16l + (size_t)(mf*16 + lr)*192;
    if (!flag){
      #pragma unroll
      for (int kf = 0; kf < 4; ++kf){
        short8v a  = ldfrag(arow + kf*32 + lk*8);
        short8v bh = ldfrag(&ztbh[lr*136 + kf*32 + lk*8]);
        short8v bl = ldfrag(&ztbl[lr*136 + kf*32 + lk*8]);
        cacc = __builtin_amdgcn_mfma_f32_16x16x32_bf16(a, bh, cacc, 0,0,0);
        cacc = __builtin_amdgcn_mfma_f32_16x16x32_bf16(a, bl, cacc, 0,0,0);
      }
      #pragma unroll
      for (int kf = 0; kf < 2; ++kf){
        short8v a  = ldfrag(arow + 128 + kf*32 + lk*8);
        short8v bh = ldfrag(hrow + kf*32 + lk*8);
        short8v bl = ldfrag(hrowl + kf*32 + lk*8);
        cacc = __builtin_amdgcn_mfma_f32_16x16x32_bf16(a, bh, cacc, 0,0,0);
        cacc = __builtin_amdgcn_mfma_f32_16x16x32_bf16(a, bl, cacc, 0,0,0);
      }
    } else {
      #pragma unroll
      for (int kf = 0; kf < 4; ++kf){
        short8v a  = ldfrag(arow + kf*32 + lk*8);
        short8v al = ldfrag(arowl + kf*32 + lk*8);
        short8v bh = ldfrag(&ztbh[lr*136 + kf*32 + lk*8]);
        short8v bl = ldfrag(&ztbl[lr*136 + kf*32 + lk*8]);
        cacc = __builtin_amdgcn_mfma_f32_16x16x32_bf16(a,  bh, cacc, 0,0,0);
        cacc = __builtin_amdgcn_mfma_f32_16x16x32_bf16(a,  bl, cacc, 0,0,0);
        cacc = __builtin_amdgcn_mfma_f32_16x16x32_bf16(al, bh, cacc, 0,0,0);
      }
      #pragma unroll
      for (int kf = 0; kf < 2; ++kf){
        short8v a  = ldfrag(arow + 128 + kf*32 + lk*8);
        short8v al = ldfrag(arowl + 128 + kf*32 + lk*8);
        short8v bh = ldfrag(hrow + kf*32 + lk*8);
        short8v bl = ldfrag(hrowl + kf*32 + lk*8);
        cacc = __builtin_amdgcn_mfma_f32_16x16x32_bf16(a,  bh, cacc, 0,0,0);
        cacc = __builtin_amdgcn_mfma_f32_16x16x32_bf16(a,  bl, cacc, 0,0,0);
        cacc = __builtin_amdgcn_mfma_f32_16x16x32_bf16(al, bh, cacc, 0,0,0);
      }
    }
    int r0 = mf*16 + lk*4;
    #pragma unroll
    for (int q = 0; q < 4; ++q)
      cb[(r0+q)*17 + lr] = cacc[q] + smalls[O_MB + r0 + q];
  }
  __syncthreads();

  // ---------------- gating: 1024 threads, one (ch,px) each ----------------
  {
    int gpx = tid >> 6, ch = tid & 63;
    float mo = cb[ch*17 + gpx];
    float mg = cb[(64+ch)*17 + gpx];
    float mi = cb[(128+ch)*17 + gpx];
    float mold = ml[ch*17 + gpx];
    float gi = sigm(mi);
    float mnew = (1.0f-gi)*mold + gi*tanhc(mg);
    float ho = sigm(mo)*mnew;
    ho_s[ch*17+gpx] = ho;
    mn_s[ch*17+gpx] = mnew;
  }
  __syncthreads();
  // loop 1 (pp-fastest): mst + out — both coalesced in n
  {
    int ch = tid >> 4, pp = tid & 15;
    int n = n0 + pp;
    size_t gidx = ((size_t)b*64 + ch)*1024 + n;
    mst[gidx] = mn_s[ch*17+pp];
    float ho = ho_s[ch*17+pp];
    size_t oidx = ((size_t)(b*64+ch)*8 + t)*1024 + n;
    if (flag) ((float*)outraw)[oidx] = ho;
    else      ((bf16*)outraw)[oidx] = __float2bfloat16(ho);
  }
  // loop 2 (ch-fastest): T-layout arrays — coalesced 2B stores
  {
    int pp = tid >> 6, ch = tid & 63;
    int n = n0 + pp;
    size_t tix = ((size_t)b*1024 + n)*64 + ch;
    float ho = ho_s[ch*17+pp];
    float mn = mn_s[ch*17+pp];
    ushort hb_ = f2bu(ho);
    hth[tix] = hb_;
    htl[tix] = f2bu(ho - bu2f(hb_));
    ushort mh_ = f2bu(mn);
    mth[tix] = mh_;
    mtl[tix] = f2bu(mn - bu2f(mh_));
  }
}

extern "C" void kernel_launch(void* const* d_in, const int* in_sizes, int n_in,
                              void* d_out, int out_size, void* d_ws, size_t ws_size,
                              hipStream_t stream)
{
  float* ws = (float*)d_ws;
  int* flag = (int*)(ws + WS_FLAG);
  float* c    = ws + WS_C;
  float* m    = ws + WS_M;
  float* gxg  = ws + WS_GXG;
  ushort* gxo   = (ushort*)(ws + WS_GXO);
  ushort* qb16  = (ushort*)(ws + WS_QB16);
  ushort* khb16 = (ushort*)(ws + WS_KHB16);
  ushort* kmb16 = (ushort*)(ws + WS_KMB16);
  ushort* vth16 = (ushort*)(ws + WS_VTH16);
  ushort* vtm16 = (ushort*)(ws + WS_VTM16);
  ushort* mth   = (ushort*)(ws + WS_MTH);
  ushort* mtl   = (ushort*)(ws + WS_MTL);
  ushort* hnth  = (ushort*)(ws + WS_HNTH);
  ushort* hntl  = (ushort*)(ws + WS_HNTL);
  ushort* zw16h = (ushort*)(ws + WS_ZW16H);
  ushort* zw16l = (ushort*)(ws + WS_ZW16L);
  ushort* mw16h = (ushort*)(ws + WS_MW16H);
  ushort* mw16l = (ushort*)(ws + WS_MW16L);
  ushort* wxah  = (ushort*)(ws + WS_WXAH);
  ushort* wxal  = (ushort*)(ws + WS_WXAL);
  ushort* whah  = (ushort*)(ws + WS_WHAH);
  ushort* whal  = (ushort*)(ws + WS_WHAL);
  ushort* xt_hi = (ushort*)(ws + WS_XTHI);
  ushort* xt_lo = (ushort*)(ws + WS_XTLO);
  ushort* ht_hi = (ushort*)(ws + WS_HTHI);
  ushort* ht_lo = (ushort*)(ws + WS_HTLO);
  ushort* pwh   = (ushort*)(ws + WS_PWH);
  ushort* pwl   = (ushort*)(ws + WS_PWL);

  k_probe<<<1, 256, 0, stream>>>((const unsigned int*)d_in[0], flag);
  P18 pk;
  for (int i = 0; i < 18; ++i) pk.p[i] = d_in[2 + i];
  k_wconv<<<dim3(64,18), 256, 0, stream>>>(pk, flag, ws);
  k_init<<<3072, 256, 0, stream>>>(d_in[1], flag, ws);
  k_xt<<<dim3(16,32), 256, 0, stream>>>(d_in[0], flag, ws);
  k_wtrans<<<144, 256, 0, stream>>>(ws);
  k_convx<<<dim3(64,2,32), 512, 0, stream>>>(flag, wxah, wxal, xt_hi, xt_lo, gxg, gxo);

  for (int t = 0; t < 8; ++t){
    k_convp<<<dim3(64,4), 1024, 0, stream>>>(flag, whah, whal, ht_hi, ht_lo,
                                             gxg, gxo, ws, c, pwh, pwl, mth, mtl,
                                             hnth, hntl, qb16, khb16, kmb16,
                                             vth16, vtm16, t);
    k_fattz<<<dim3(64,4), 1024, 0, stream>>>(qb16, khb16, kmb16, vth16, vtm16,
                                             hnth, hntl, ws, zw16h, zw16l, mw16h, mw16l,
                                             flag, m, mth, mtl, ht_hi, ht_lo, d_out, t);
  }
  (void)in_sizes; (void)n_in; (void)out_size; (void)ws_size;
}